// Round 8
// baseline (332.733 us; speedup 1.0000x reference)
//
#include <hip/hip_runtime.h>
#include <hip/hip_bf16.h>

#define NNODES 50000
#define NROWP  50176   // padded row count (multiple of 64) for GEMM tiles
#define NEDGES 800000
#define KHOP 3
#define SCAN_NB 49     // ceil(NNODES / 1024)
#define NBKT 196       // ceil(50176/256) buckets of 256 nodes
#define BCAP 6144      // entries per bucket (mean 4082, sd ~64 -> safe)
#define ABLK 400       // pass-A blocks
#define ACH  2000      // edges per pass-A block
#define PXWG 50000     // prop128x workgroups: 6250*8 (4 nodes/wg per col-block)

typedef __attribute__((ext_vector_type(8))) short short8v;
typedef __attribute__((ext_vector_type(8))) __bf16 bf16x8;
typedef __attribute__((ext_vector_type(4))) float f32x4;

__device__ inline unsigned short f2bf(float f) {
  unsigned u = __builtin_bit_cast(unsigned, f);
  u += 0x7fffu + ((u >> 16) & 1u);   // RNE
  return (unsigned short)(u >> 16);
}
__device__ inline float bflo(unsigned u) { return __builtin_bit_cast(float, u << 16); }
__device__ inline float bfhi(unsigned u) { return __builtin_bit_cast(float, u & 0xffff0000u); }

__device__ inline void gload_lds16(const void* g, void* l) {
  __builtin_amdgcn_global_load_lds(
      (const __attribute__((address_space(1))) unsigned int*)g,
      (__attribute__((address_space(3))) unsigned int*)l, 16, 0, 0);
}

__device__ inline f32x4 mfma_bf16(bf16x8 a, bf16x8 b, f32x4 c) {
  return __builtin_amdgcn_mfma_f32_16x16x32_bf16(a, b, c, 0, 0, 0);
}

__device__ inline void fma4(float* acc, float w, uint2 v) {
  acc[0] = fmaf(w, bflo(v.x), acc[0]);
  acc[1] = fmaf(w, bfhi(v.x), acc[1]);
  acc[2] = fmaf(w, bflo(v.y), acc[2]);
  acc[3] = fmaf(w, bfhi(v.y), acc[3]);
}

// ---------------- Pass A: bucket edges by dst>>8 ----------------
__global__ __launch_bounds__(256) void bucketA_kernel(
    const int* __restrict__ src, const int* __restrict__ dst,
    int* __restrict__ bcur, int2* __restrict__ bkt) {
  __shared__ int2 eb[ACH];
  __shared__ int hist[256];
  __shared__ int base[256];
  int tid = threadIdx.x;
  int e0 = blockIdx.x * ACH;
  int cnt = NEDGES - e0; if (cnt > ACH) cnt = ACH;
  hist[tid] = 0;
  __syncthreads();
  for (int i = tid; i < cnt; i += 256) {
    int s = src[e0 + i], d = dst[e0 + i];
    eb[i] = make_int2(s, d);
    atomicAdd(&hist[d >> 8], 1);
  }
  __syncthreads();
  base[tid] = atomicAdd(&bcur[tid], hist[tid]);
  hist[tid] = 0;
  __syncthreads();
  for (int i = tid; i < cnt; i += 256) {
    int2 e = eb[i];
    int b = e.y >> 8;
    int off = atomicAdd(&hist[b], 1);
    bkt[(size_t)b * BCAP + base[b] + off] = e;
  }
}

// ---------------- per-bucket node histogram ----------------
__global__ __launch_bounds__(256) void histB_kernel(
    const int* __restrict__ bcur, const int2* __restrict__ bkt,
    int* __restrict__ cnt, int n) {
  __shared__ int h[256];
  int b = blockIdx.x, tid = threadIdx.x;
  h[tid] = 0;
  __syncthreads();
  int sz = bcur[b];
  for (int i = tid; i < sz; i += 256)
    atomicAdd(&h[bkt[(size_t)b * BCAP + i].y & 255], 1);
  __syncthreads();
  int node = b * 256 + tid;
  if (node < n) cnt[node] = h[tid];
}

// --- hierarchical exclusive scan: bsum -> bscan -> bfinal (+dis fused) ---
__global__ __launch_bounds__(256) void bsum_kernel(const int* __restrict__ cnt,
                                                   int* __restrict__ bsums, int n) {
  __shared__ int sd[256];
  int tid = threadIdx.x;
  int base = blockIdx.x * 1024 + tid * 4;
  int s = 0;
  if (base + 4 <= n) {
    int4 v = *(const int4*)&cnt[base];
    s = v.x + v.y + v.z + v.w;
  }
  sd[tid] = s;
  __syncthreads();
  for (int o = 128; o; o >>= 1) {
    if (tid < o) sd[tid] += sd[tid + o];
    __syncthreads();
  }
  if (tid == 0) bsums[blockIdx.x] = sd[0];
}

__global__ __launch_bounds__(64) void bscan_kernel(const int* __restrict__ bsums,
                                                   int* __restrict__ boff,
                                                   int* __restrict__ row_ptr,
                                                   int nb, int n) {
  int tid = threadIdx.x;
  int own = (tid < nb) ? bsums[tid] : 0;
  int v = own;
#pragma unroll
  for (int o = 1; o < 64; o <<= 1) {
    int t = __shfl_up(v, o, 64);
    if (tid >= o) v += t;
  }
  if (tid < nb) boff[tid] = v - own;   // exclusive block offset
  if (tid == 63) row_ptr[n] = v;       // total edge count
}

__global__ __launch_bounds__(256) void bfinal_kernel(const int* __restrict__ cnt,
                                                     const int* __restrict__ boff,
                                                     int* __restrict__ row_ptr,
                                                     float* __restrict__ dis, int n) {
  __shared__ int sd[256];
  int tid = threadIdx.x;
  int base = blockIdx.x * 1024 + tid * 4;
  int4 v = make_int4(0, 0, 0, 0);
  bool ok = (base + 4 <= n);
  if (ok) v = *(const int4*)&cnt[base];
  int s = v.x + v.y + v.z + v.w;
  sd[tid] = s;
  __syncthreads();
  for (int o = 1; o < 256; o <<= 1) {
    int t = (tid >= o) ? sd[tid - o] : 0;
    __syncthreads();
    sd[tid] += t;
    __syncthreads();
  }
  if (ok) {
    int run = boff[blockIdx.x] + sd[tid] - s;  // exclusive prefix
    int4 rp;
    rp.x = run;
    rp.y = run + v.x;
    rp.z = rp.y + v.y;
    rp.w = rp.z + v.z;
    *(int4*)&row_ptr[base] = rp;
    float4 dv;
    dv.x = (v.x > 0) ? rsqrtf((float)v.x) : 0.f;
    dv.y = (v.y > 0) ? rsqrtf((float)v.y) : 0.f;
    dv.z = (v.z > 0) ? rsqrtf((float)v.z) : 0.f;
    dv.w = (v.w > 0) ? rsqrtf((float)v.w) : 0.f;
    *(float4*)&dis[base] = dv;
  }
}

// ---------------- Pass B: per-bucket scatter into CSR ----------------
__global__ __launch_bounds__(256) void scatB_kernel(
    const int* __restrict__ bcur, const int2* __restrict__ bkt,
    const int* __restrict__ row_ptr, const float* __restrict__ dis,
    int2* __restrict__ csr, int n) {
  __shared__ int cur[256];
  int b = blockIdx.x, tid = threadIdx.x;
  int node = b * 256 + tid;
  cur[tid] = (node < n) ? row_ptr[node] : 0;
  __syncthreads();
  int sz = bcur[b];
  for (int i = tid; i < sz; i += 256) {
    int2 e = bkt[(size_t)b * BCAP + i];
    int pos = atomicAdd(&cur[e.y & 255], 1);
    int2 ent;
    ent.x = e.x;
    ent.y = __float_as_int(dis[e.x] * dis[e.y]);
    csr[pos] = ent;
  }
}

// ---------------- fused weight transforms ----------------
__global__ void wprep_kernel(const float* __restrict__ W1, const float* __restrict__ W2,
                             unsigned short* __restrict__ W1t,
                             unsigned short* __restrict__ W2pt) {
  int t = blockIdx.x * blockDim.x + threadIdx.x;
  if (t < 512 * 128) {
    int c = t >> 9, k = t & 511;
    W1t[t] = f2bf(W1[(size_t)k * 128 + c]);
  } else if (t < 512 * 128 + 160 * 128) {
    int u = t - 512 * 128;
    int q = u >> 7, r = u & 127;
    int k = q / 40, c = q - k * 40;
    W2pt[u] = f2bf(W2[(size_t)(k * 128 + r) * 40 + c]);
  }
}

// ---------------- x -> bf16 into P hop-0 (col-blocked [4][NROWP][32]) ----------------
__global__ void copyx_kernel(const float* __restrict__ x, unsigned short* __restrict__ Pb, int n) {
  int t = blockIdx.x * blockDim.x + threadIdx.x;
  int i = t >> 4;
  int sl = t & 15;
  if (i < n) {
    int c = sl >> 2, q = sl & 3;   // col-block, 8-col group
    float4 v0 = *(const float4*)&x[(size_t)i * 128 + c * 32 + q * 8];
    float4 v1 = *(const float4*)&x[(size_t)i * 128 + c * 32 + q * 8 + 4];
    uint4 r;
    r.x = (unsigned)f2bf(v0.x) | ((unsigned)f2bf(v0.y) << 16);
    r.y = (unsigned)f2bf(v0.z) | ((unsigned)f2bf(v0.w) << 16);
    r.z = (unsigned)f2bf(v1.x) | ((unsigned)f2bf(v1.y) << 16);
    r.w = (unsigned)f2bf(v1.z) | ((unsigned)f2bf(v1.w) << 16);
    *(uint4*)(Pb + ((size_t)c * NROWP + i) * 32 + q * 8) = r;
  }
}

// ---------------- 128-dim propagation, col-blocked + XCD-pinned ----------------
// in/out: [4][NROWP][32] bf16. col_block = (wgid&7)>>1 so each XCD's gather
// working set is one 3.2MB block (fits 4MB per-XCD L2). 4 waves/wg = 4 nodes.
__global__ __launch_bounds__(256) void prop128x_kernel(
    const unsigned short* __restrict__ in, unsigned short* __restrict__ out,
    const int* __restrict__ row_ptr, const int2* __restrict__ csr, int n) {
  int wgid = blockIdx.x;
  int xcd = wgid & 7;
  int cb = xcd >> 1;
  int chunk = (wgid >> 3) * 2 + (xcd & 1);
  int node = chunk * 4 + (threadIdx.x >> 6);
  int lane = threadIdx.x & 63;
  if (node >= n) return;
  int beg = row_ptr[node], end = row_ptr[node + 1];
  int deg = end - beg;
  int2 ent = make_int2(0, 0);
  if (lane < deg) ent = csr[beg + lane];
  const int slot = lane >> 3, sub = lane & 7;
  const unsigned short* inb = in + (size_t)cb * NROWP * 32;
  float acc[4] = {0.f, 0.f, 0.f, 0.f};
  int m = deg < 64 ? deg : 64;
  for (int j = 0; j < m; j += 8) {
    int idx = j + slot;
    bool act = idx < m;
    int ic = act ? idx : m - 1;
    int s = __shfl(ent.x, ic, 64);
    float w = __int_as_float(__shfl(ent.y, ic, 64));
    if (!act) w = 0.f;
    uint2 v = *(const uint2*)(inb + (size_t)s * 32 + sub * 4);
    fma4(acc, w, v);
  }
  for (int t = beg + 64; t < end; ++t) {   // rare deg>64 tail
    int2 e0 = csr[t];
    float w = (slot == 0) ? __int_as_float(e0.y) : 0.f;
    uint2 v = *(const uint2*)(inb + (size_t)e0.x * 32 + sub * 4);
    fma4(acc, w, v);
  }
#pragma unroll
  for (int i = 0; i < 4; ++i) {
    acc[i] += __shfl_xor(acc[i], 8, 64);
    acc[i] += __shfl_xor(acc[i], 16, 64);
    acc[i] += __shfl_xor(acc[i], 32, 64);
  }
  if (slot == 0) {
    uint2 r;
    r.x = (unsigned)f2bf(acc[0]) | ((unsigned)f2bf(acc[1]) << 16);
    r.y = (unsigned)f2bf(acc[2]) | ((unsigned)f2bf(acc[3]) << 16);
    *(uint2*)(out + ((size_t)cb * NROWP + node) * 32 + sub * 4) = r;
  }
}

// ---------------- GEMM1 (MFMA): H = relu(P @ W1 + b1); A in col-blocked layout ----------------
__global__ __launch_bounds__(256) void gemm1m_kernel(
    const unsigned short* __restrict__ A,    // [16][NROWP][32] bf16 (4 hops x 4 blocks)
    const unsigned short* __restrict__ Bt,   // [128][512] bf16 (W1 transposed)
    const float* __restrict__ bias,
    unsigned short* __restrict__ H) {        // [NROWP][128] bf16
  __shared__ short As[64 * 32];
  __shared__ short Bs[128 * 32];
  const int tid = threadIdx.x;
  const int lane = tid & 63;
  const int w = tid >> 6;
  const int wr = w & 1;
  const int wc = w >> 1;
  const int row0 = blockIdx.x * 64;
  f32x4 acc[2][4];
#pragma unroll
  for (int i = 0; i < 2; ++i)
#pragma unroll
    for (int j = 0; j < 4; ++j) acc[i][j] = (f32x4)0.f;

  const int lrow = lane >> 2;
  const int lkp = lane & 3;

  for (int k0 = 0; k0 < 512; k0 += 32) {
    const int blk = k0 >> 5;   // hop*4 + col_block
    gload_lds16(A + ((size_t)blk * NROWP + row0 + w * 16 + lrow) * 32 + lkp * 8, &As[w * 512]);
    gload_lds16(Bt + (size_t)(w * 16 + lrow) * 512 + k0 + lkp * 8, &Bs[w * 512]);
    gload_lds16(Bt + (size_t)((w + 4) * 16 + lrow) * 512 + k0 + lkp * 8, &Bs[(w + 4) * 512]);
    __syncthreads();
    const int kg = lane >> 4, rr = lane & 15;
    bf16x8 af[2], bfr[4];
#pragma unroll
    for (int mr = 0; mr < 2; ++mr)
      af[mr] = __builtin_bit_cast(bf16x8,
          *(const short8v*)&As[(wr * 32 + mr * 16 + rr) * 32 + kg * 8]);
#pragma unroll
    for (int nr = 0; nr < 4; ++nr)
      bfr[nr] = __builtin_bit_cast(bf16x8,
          *(const short8v*)&Bs[(wc * 64 + nr * 16 + rr) * 32 + kg * 8]);
#pragma unroll
    for (int mr = 0; mr < 2; ++mr)
#pragma unroll
      for (int nr = 0; nr < 4; ++nr)
        acc[mr][nr] = mfma_bf16(af[mr], bfr[nr], acc[mr][nr]);
    __syncthreads();
  }
  const int cg = lane >> 4, cl = lane & 15;
#pragma unroll
  for (int mr = 0; mr < 2; ++mr)
#pragma unroll
    for (int nr = 0; nr < 4; ++nr) {
      int col = wc * 64 + nr * 16 + cl;
      float bv = bias[col];
#pragma unroll
      for (int j = 0; j < 4; ++j) {
        int row = row0 + wr * 32 + mr * 16 + cg * 4 + j;
        H[(size_t)row * 128 + col] = f2bf(fmaxf(acc[mr][nr][j] + bv, 0.f));
      }
    }
}

// ---------------- GEMM2 (MFMA): Gk[N,64-padded] bf16, k=0..3 ----------------
__global__ __launch_bounds__(256) void gemm2m_kernel(
    const unsigned short* __restrict__ A,    // [NROWP][128] bf16
    const unsigned short* __restrict__ Bt,   // [160][128] bf16
    unsigned short* __restrict__ G) {        // 4 x [NROWP][64] bf16 (cols 40..63 pad)
  __shared__ short As[64 * 32];
  __shared__ short Bs[160 * 32];
  const int tid = threadIdx.x;
  const int lane = tid & 63;
  const int w = tid >> 6;
  const int row0 = blockIdx.x * 64;
  f32x4 acc[10];
#pragma unroll
  for (int i = 0; i < 10; ++i) acc[i] = (f32x4)0.f;
  const int lrow = lane >> 2, lkp = lane & 3;

  for (int k0 = 0; k0 < 128; k0 += 32) {
    gload_lds16(A + (size_t)(row0 + w * 16 + lrow) * 128 + k0 + lkp * 8, &As[w * 512]);
    for (int c = w; c < 10; c += 4)
      gload_lds16(Bt + (size_t)(c * 16 + lrow) * 128 + k0 + lkp * 8, &Bs[c * 512]);
    __syncthreads();
    const int kg = lane >> 4, rr = lane & 15;
    bf16x8 af = __builtin_bit_cast(bf16x8,
        *(const short8v*)&As[(w * 16 + rr) * 32 + kg * 8]);
#pragma unroll
    for (int nr = 0; nr < 10; ++nr) {
      bf16x8 bfr = __builtin_bit_cast(bf16x8,
          *(const short8v*)&Bs[(nr * 16 + rr) * 32 + kg * 8]);
      acc[nr] = mfma_bf16(af, bfr, acc[nr]);
    }
    __syncthreads();
  }
  const int cg = lane >> 4, cl = lane & 15;
#pragma unroll
  for (int nr = 0; nr < 10; ++nr) {
    int col = nr * 16 + cl;      // 0..159
    int k = col / 40;            // hop block
    int o = col - k * 40;
#pragma unroll
    for (int j = 0; j < 4; ++j) {
      int row = row0 + w * 16 + cg * 4 + j;
      G[(size_t)k * NROWP * 64 + (size_t)row * 64 + o] = f2bf(acc[nr][j]);
    }
  }
}

// ---------------- 40(64-pad)-dim propagation: 4 slots x 16 lanes, 8B loads ----------------
__global__ __launch_bounds__(256) void prop40c_kernel(
    const unsigned short* __restrict__ in,   // [n][64] bf16 (pad cols garbage-ok)
    const unsigned short* __restrict__ add,  // [n][64]
    unsigned short* __restrict__ out,        // [n][64]
    const int* __restrict__ row_ptr, const int2* __restrict__ csr, int n) {
  int node = (int)((blockIdx.x * blockDim.x + threadIdx.x) >> 6);
  int lane = threadIdx.x & 63;
  if (node >= n) return;
  int beg = row_ptr[node], end = row_ptr[node + 1];
  int deg = end - beg;
  int2 ent = make_int2(0, 0);
  if (lane < deg) ent = csr[beg + lane];
  const int grp = lane >> 4, sub = lane & 15;
  float acc[4] = {0.f, 0.f, 0.f, 0.f};
  if (grp == 0) {
    uint2 a = *(const uint2*)(add + (size_t)node * 64 + sub * 4);
    acc[0] = bflo(a.x); acc[1] = bfhi(a.x);
    acc[2] = bflo(a.y); acc[3] = bfhi(a.y);
  }
  int m = deg < 64 ? deg : 64;
  for (int j = 0; j < m; j += 4) {
    int idx = j + grp;
    bool act = idx < m;
    int ic = act ? idx : m - 1;
    int s = __shfl(ent.x, ic, 64);
    float w = __int_as_float(__shfl(ent.y, ic, 64));
    if (!act) w = 0.f;
    uint2 v = *(const uint2*)(in + (size_t)s * 64 + sub * 4);
    fma4(acc, w, v);
  }
  for (int t = beg + 64; t < end; ++t) {
    int2 e0 = csr[t];
    float w = (grp == 0) ? __int_as_float(e0.y) : 0.f;
    uint2 v = *(const uint2*)(in + (size_t)e0.x * 64 + sub * 4);
    fma4(acc, w, v);
  }
#pragma unroll
  for (int i = 0; i < 4; ++i) {
    acc[i] += __shfl_xor(acc[i], 16, 64);
    acc[i] += __shfl_xor(acc[i], 32, 64);
  }
  if (grp == 0) {
    uint2 r;
    r.x = (unsigned)f2bf(acc[0]) | ((unsigned)f2bf(acc[1]) << 16);
    r.y = (unsigned)f2bf(acc[2]) | ((unsigned)f2bf(acc[3]) << 16);
    *(uint2*)(out + (size_t)node * 64 + sub * 4) = r;
  }
}

// ---------------- final hop fused with bias + log_softmax ----------------
__global__ __launch_bounds__(256) void prop40c_lsm_kernel(
    const unsigned short* __restrict__ in,   // [n][64]
    const unsigned short* __restrict__ add,  // [n][64]
    const float* __restrict__ b2,
    float* __restrict__ out,                 // [n][40] f32
    const int* __restrict__ row_ptr, const int2* __restrict__ csr, int n) {
  int node = (int)((blockIdx.x * blockDim.x + threadIdx.x) >> 6);
  int lane = threadIdx.x & 63;
  if (node >= n) return;
  int beg = row_ptr[node], end = row_ptr[node + 1];
  int deg = end - beg;
  int2 ent = make_int2(0, 0);
  if (lane < deg) ent = csr[beg + lane];
  const int grp = lane >> 4, sub = lane & 15;
  float acc[4] = {0.f, 0.f, 0.f, 0.f};
  if (grp == 0) {
    uint2 a = *(const uint2*)(add + (size_t)node * 64 + sub * 4);
    acc[0] = bflo(a.x); acc[1] = bfhi(a.x);
    acc[2] = bflo(a.y); acc[3] = bfhi(a.y);
  }
  int m = deg < 64 ? deg : 64;
  for (int j = 0; j < m; j += 4) {
    int idx = j + grp;
    bool act = idx < m;
    int ic = act ? idx : m - 1;
    int s = __shfl(ent.x, ic, 64);
    float w = __int_as_float(__shfl(ent.y, ic, 64));
    if (!act) w = 0.f;
    uint2 v = *(const uint2*)(in + (size_t)s * 64 + sub * 4);
    fma4(acc, w, v);
  }
  for (int t = beg + 64; t < end; ++t) {
    int2 e0 = csr[t];
    float w = (grp == 0) ? __int_as_float(e0.y) : 0.f;
    uint2 v = *(const uint2*)(in + (size_t)e0.x * 64 + sub * 4);
    fma4(acc, w, v);
  }
#pragma unroll
  for (int i = 0; i < 4; ++i) {
    acc[i] += __shfl_xor(acc[i], 16, 64);
    acc[i] += __shfl_xor(acc[i], 32, 64);
  }
  bool val = (sub < 10);
  float vv[4];
  if (val) {
    float4 bv = *(const float4*)(b2 + sub * 4);
    vv[0] = acc[0] + bv.x; vv[1] = acc[1] + bv.y;
    vv[2] = acc[2] + bv.z; vv[3] = acc[3] + bv.w;
  } else {
    vv[0] = vv[1] = vv[2] = vv[3] = -__builtin_inff();
  }
  float mx = fmaxf(fmaxf(vv[0], vv[1]), fmaxf(vv[2], vv[3]));
#pragma unroll
  for (int o = 1; o < 16; o <<= 1) mx = fmaxf(mx, __shfl_xor(mx, o, 64));
  float s = 0.f;
  if (val)
    s = expf(vv[0] - mx) + expf(vv[1] - mx) + expf(vv[2] - mx) + expf(vv[3] - mx);
#pragma unroll
  for (int o = 1; o < 16; o <<= 1) s += __shfl_xor(s, o, 64);
  if (val) {
    float ls = logf(s);
    float4 o4;
    o4.x = vv[0] - mx - ls; o4.y = vv[1] - mx - ls;
    o4.z = vv[2] - mx - ls; o4.w = vv[3] - mx - ls;
    *(float4*)(out + (size_t)node * 40 + sub * 4) = o4;
  }
}

extern "C" void kernel_launch(void* const* d_in, const int* in_sizes, int n_in,
                              void* d_out, int out_size, void* d_ws, size_t ws_size,
                              hipStream_t stream) {
  const float* x  = (const float*)d_in[0];
  const int*   ei = (const int*)d_in[1];
  const float* W1 = (const float*)d_in[2];
  const float* b1 = (const float*)d_in[3];
  const float* W2 = (const float*)d_in[4];
  const float* b2 = (const float*)d_in[5];
  const int* srcv = ei;
  const int* dstv = ei + NEDGES;
  float* out = (float*)d_out;

  char* wsb = (char*)d_ws;
  size_t off = 0;
  auto alloc = [&](size_t bytes) {
    char* p = wsb + off;
    off += (bytes + 255) & ~(size_t)255;
    return p;
  };
  int*            cnt     = (int*)            alloc((size_t)NNODES * 4);
  float*          dis     = (float*)          alloc((size_t)NNODES * 4);
  int*            row_ptr = (int*)            alloc(((size_t)NNODES + 1) * 4);
  int*            bcur    = (int*)            alloc((size_t)256 * 4);
  int*            bsums   = (int*)            alloc((size_t)SCAN_NB * 4);
  int*            boff    = (int*)            alloc((size_t)SCAN_NB * 4);
  int2*           bkt     = (int2*)           alloc((size_t)NBKT * BCAP * 8);
  int2*           csr     = (int2*)           alloc((size_t)NEDGES * 8);
  unsigned short* W1t     = (unsigned short*) alloc((size_t)128 * 512 * 2);
  unsigned short* W2pt    = (unsigned short*) alloc((size_t)160 * 128 * 2);
  unsigned short* P       = (unsigned short*) alloc((size_t)NROWP * 512 * 2);  // [16][NROWP][32]
  unsigned short* H       = (unsigned short*) alloc((size_t)NROWP * 128 * 2);
  unsigned short* G       = (unsigned short*) alloc((size_t)4 * NROWP * 64 * 2);
  unsigned short* tb      = (unsigned short*) alloc((size_t)NNODES * 64 * 2);
  unsigned short* t2      = (unsigned short*) alloc((size_t)NNODES * 64 * 2);

  unsigned short* G0 = G;
  unsigned short* G1 = G + (size_t)1 * NROWP * 64;
  unsigned short* G2 = G + (size_t)2 * NROWP * 64;
  unsigned short* G3 = G + (size_t)3 * NROWP * 64;

  hipMemsetAsync(bcur, 0, 256 * 4, stream);
  bucketA_kernel<<<ABLK, 256, 0, stream>>>(srcv, dstv, bcur, bkt);
  histB_kernel<<<NBKT, 256, 0, stream>>>(bcur, bkt, cnt, NNODES);
  bsum_kernel<<<SCAN_NB, 256, 0, stream>>>(cnt, bsums, NNODES);
  bscan_kernel<<<1, 64, 0, stream>>>(bsums, boff, row_ptr, SCAN_NB, NNODES);
  bfinal_kernel<<<SCAN_NB, 256, 0, stream>>>(cnt, boff, row_ptr, dis, NNODES);
  scatB_kernel<<<NBKT, 256, 0, stream>>>(bcur, bkt, row_ptr, dis, csr, NNODES);
  wprep_kernel<<<(512 * 128 + 160 * 128 + 255) / 256, 256, 0, stream>>>(W1, W2, W1t, W2pt);
  copyx_kernel<<<((NNODES * 16) + 255) / 256, 256, 0, stream>>>(x, P, NNODES);

  // Layer 1: hop k blocks = A_hat^k x, col-blocked [4][NROWP][32] per hop
  const size_t hopstride = (size_t)4 * NROWP * 32;
  for (int k = 1; k <= KHOP; ++k)
    prop128x_kernel<<<PXWG, 256, 0, stream>>>(P + hopstride * (k - 1), P + hopstride * k,
                                              row_ptr, csr, NNODES);
  const int gemm_blocks = (NNODES + 63) / 64;  // 782; rows < NROWP
  gemm1m_kernel<<<gemm_blocks, 256, 0, stream>>>(P, W1t, b1, H);
  gemm2m_kernel<<<gemm_blocks, 256, 0, stream>>>(H, W2pt, G);
  // Horner (bf16 storage, fp32 accum): tb = A*G3 + G2 ; t2 = A*tb + G1 ; out = lsm(A*t2 + G0 + b2)
  const int prop_blocks = (NNODES * 64 + 255) / 256;
  prop40c_kernel<<<prop_blocks, 256, 0, stream>>>(G3, G2, tb, row_ptr, csr, NNODES);
  prop40c_kernel<<<prop_blocks, 256, 0, stream>>>(tb, G1, t2, row_ptr, csr, NNODES);
  prop40c_lsm_kernel<<<prop_blocks, 256, 0, stream>>>(t2, G0, b2, out, row_ptr, csr, NNODES);
}

// Round 9
// 268.671 us; speedup vs baseline: 1.2384x; 1.2384x over previous
//
#include <hip/hip_runtime.h>
#include <hip/hip_bf16.h>

#define NNODES 50000
#define NROWP  50176   // padded row count (multiple of 64) for GEMM tiles
#define NEDGES 800000
#define KHOP 3
#define SCAN_NB 49     // ceil(NNODES / 1024)
#define NBKT 196       // ceil(50176/256) buckets of 256 nodes
#define BCAP 6144      // entries per bucket (mean 4082, sd ~64 -> safe)
#define ABLK 400       // pass-A blocks
#define ACH  2000      // edges per pass-A block

typedef __attribute__((ext_vector_type(8))) short short8v;
typedef __attribute__((ext_vector_type(8))) __bf16 bf16x8;
typedef __attribute__((ext_vector_type(4))) float f32x4;

__device__ inline unsigned short f2bf(float f) {
  unsigned u = __builtin_bit_cast(unsigned, f);
  u += 0x7fffu + ((u >> 16) & 1u);   // RNE
  return (unsigned short)(u >> 16);
}
__device__ inline float bflo(unsigned u) { return __builtin_bit_cast(float, u << 16); }
__device__ inline float bfhi(unsigned u) { return __builtin_bit_cast(float, u & 0xffff0000u); }

__device__ inline void gload_lds16(const void* g, void* l) {
  __builtin_amdgcn_global_load_lds(
      (const __attribute__((address_space(1))) unsigned int*)g,
      (__attribute__((address_space(3))) unsigned int*)l, 16, 0, 0);
}

__device__ inline f32x4 mfma_bf16(bf16x8 a, bf16x8 b, f32x4 c) {
  return __builtin_amdgcn_mfma_f32_16x16x32_bf16(a, b, c, 0, 0, 0);
}

__device__ inline void fma8(float* acc, float w, short8v v) {
  uint4 u = __builtin_bit_cast(uint4, v);
  acc[0] = fmaf(w, bflo(u.x), acc[0]);
  acc[1] = fmaf(w, bfhi(u.x), acc[1]);
  acc[2] = fmaf(w, bflo(u.y), acc[2]);
  acc[3] = fmaf(w, bfhi(u.y), acc[3]);
  acc[4] = fmaf(w, bflo(u.z), acc[4]);
  acc[5] = fmaf(w, bfhi(u.z), acc[5]);
  acc[6] = fmaf(w, bflo(u.w), acc[6]);
  acc[7] = fmaf(w, bfhi(u.w), acc[7]);
}

// ---------------- Pass A: bucket edges by dst>>8 ----------------
__global__ __launch_bounds__(256) void bucketA_kernel(
    const int* __restrict__ src, const int* __restrict__ dst,
    int* __restrict__ bcur, int2* __restrict__ bkt) {
  __shared__ int2 eb[ACH];
  __shared__ int hist[256];
  __shared__ int base[256];
  int tid = threadIdx.x;
  int e0 = blockIdx.x * ACH;
  int cnt = NEDGES - e0; if (cnt > ACH) cnt = ACH;
  hist[tid] = 0;
  __syncthreads();
  for (int i = tid; i < cnt; i += 256) {
    int s = src[e0 + i], d = dst[e0 + i];
    eb[i] = make_int2(s, d);
    atomicAdd(&hist[d >> 8], 1);
  }
  __syncthreads();
  base[tid] = atomicAdd(&bcur[tid], hist[tid]);
  hist[tid] = 0;
  __syncthreads();
  for (int i = tid; i < cnt; i += 256) {
    int2 e = eb[i];
    int b = e.y >> 8;
    int off = atomicAdd(&hist[b], 1);
    bkt[(size_t)b * BCAP + base[b] + off] = e;
  }
}

// ---------------- per-bucket node histogram ----------------
__global__ __launch_bounds__(256) void histB_kernel(
    const int* __restrict__ bcur, const int2* __restrict__ bkt,
    int* __restrict__ cnt, int n) {
  __shared__ int h[256];
  int b = blockIdx.x, tid = threadIdx.x;
  h[tid] = 0;
  __syncthreads();
  int sz = bcur[b];
  for (int i = tid; i < sz; i += 256)
    atomicAdd(&h[bkt[(size_t)b * BCAP + i].y & 255], 1);
  __syncthreads();
  int node = b * 256 + tid;
  if (node < n) cnt[node] = h[tid];
}

// --- hierarchical exclusive scan: bsum -> bscan -> bfinal (+dis fused) ---
__global__ __launch_bounds__(256) void bsum_kernel(const int* __restrict__ cnt,
                                                   int* __restrict__ bsums, int n) {
  __shared__ int sd[256];
  int tid = threadIdx.x;
  int base = blockIdx.x * 1024 + tid * 4;
  int s = 0;
  if (base + 4 <= n) {
    int4 v = *(const int4*)&cnt[base];
    s = v.x + v.y + v.z + v.w;
  }
  sd[tid] = s;
  __syncthreads();
  for (int o = 128; o; o >>= 1) {
    if (tid < o) sd[tid] += sd[tid + o];
    __syncthreads();
  }
  if (tid == 0) bsums[blockIdx.x] = sd[0];
}

__global__ __launch_bounds__(64) void bscan_kernel(const int* __restrict__ bsums,
                                                   int* __restrict__ boff,
                                                   int* __restrict__ row_ptr,
                                                   int nb, int n) {
  int tid = threadIdx.x;
  int own = (tid < nb) ? bsums[tid] : 0;
  int v = own;
#pragma unroll
  for (int o = 1; o < 64; o <<= 1) {
    int t = __shfl_up(v, o, 64);
    if (tid >= o) v += t;
  }
  if (tid < nb) boff[tid] = v - own;   // exclusive block offset
  if (tid == 63) row_ptr[n] = v;       // total edge count
}

__global__ __launch_bounds__(256) void bfinal_kernel(const int* __restrict__ cnt,
                                                     const int* __restrict__ boff,
                                                     int* __restrict__ row_ptr,
                                                     float* __restrict__ dis, int n) {
  __shared__ int sd[256];
  int tid = threadIdx.x;
  int base = blockIdx.x * 1024 + tid * 4;
  int4 v = make_int4(0, 0, 0, 0);
  bool ok = (base + 4 <= n);
  if (ok) v = *(const int4*)&cnt[base];
  int s = v.x + v.y + v.z + v.w;
  sd[tid] = s;
  __syncthreads();
  for (int o = 1; o < 256; o <<= 1) {
    int t = (tid >= o) ? sd[tid - o] : 0;
    __syncthreads();
    sd[tid] += t;
    __syncthreads();
  }
  if (ok) {
    int run = boff[blockIdx.x] + sd[tid] - s;  // exclusive prefix
    int4 rp;
    rp.x = run;
    rp.y = run + v.x;
    rp.z = rp.y + v.y;
    rp.w = rp.z + v.z;
    *(int4*)&row_ptr[base] = rp;
    float4 dv;
    dv.x = (v.x > 0) ? rsqrtf((float)v.x) : 0.f;
    dv.y = (v.y > 0) ? rsqrtf((float)v.y) : 0.f;
    dv.z = (v.z > 0) ? rsqrtf((float)v.z) : 0.f;
    dv.w = (v.w > 0) ? rsqrtf((float)v.w) : 0.f;
    *(float4*)&dis[base] = dv;
  }
}

// ---------------- Pass B: per-bucket scatter into CSR ----------------
__global__ __launch_bounds__(256) void scatB_kernel(
    const int* __restrict__ bcur, const int2* __restrict__ bkt,
    const int* __restrict__ row_ptr, const float* __restrict__ dis,
    int2* __restrict__ csr, int n) {
  __shared__ int cur[256];
  int b = blockIdx.x, tid = threadIdx.x;
  int node = b * 256 + tid;
  cur[tid] = (node < n) ? row_ptr[node] : 0;
  __syncthreads();
  int sz = bcur[b];
  for (int i = tid; i < sz; i += 256) {
    int2 e = bkt[(size_t)b * BCAP + i];
    int pos = atomicAdd(&cur[e.y & 255], 1);
    int2 ent;
    ent.x = e.x;
    ent.y = __float_as_int(dis[e.x] * dis[e.y]);
    csr[pos] = ent;
  }
}

// ---------------- fused weight transforms ----------------
__global__ void wprep_kernel(const float* __restrict__ W1, const float* __restrict__ W2,
                             unsigned short* __restrict__ W1t,
                             unsigned short* __restrict__ W2pt) {
  int t = blockIdx.x * blockDim.x + threadIdx.x;
  if (t < 512 * 128) {
    int c = t >> 9, k = t & 511;
    W1t[t] = f2bf(W1[(size_t)k * 128 + c]);
  } else if (t < 512 * 128 + 160 * 128) {
    int u = t - 512 * 128;
    int q = u >> 7, r = u & 127;
    int k = q / 40, c = q - k * 40;
    W2pt[u] = f2bf(W2[(size_t)(k * 128 + r) * 40 + c]);
  }
}

// ---------------- x -> bf16 into P block 0 ----------------
__global__ void copyx_kernel(const float* __restrict__ x, unsigned short* __restrict__ P, int n) {
  int t = blockIdx.x * blockDim.x + threadIdx.x;
  int i = t >> 5;
  int c4 = (t & 31) << 2;
  if (i < n) {
    float4 v = *(const float4*)&x[(size_t)i * 128 + c4];
    unsigned lo = (unsigned)f2bf(v.x) | ((unsigned)f2bf(v.y) << 16);
    unsigned hi = (unsigned)f2bf(v.z) | ((unsigned)f2bf(v.w) << 16);
    uint2 o; o.x = lo; o.y = hi;
    *(uint2*)&P[(size_t)i * 512 + c4] = o;
  }
}

// ---------------- 128-dim bf16 propagation: 4 slots x 16 lanes, direct CSR loads ----------------
__global__ __launch_bounds__(256) void prop128c_kernel(
    const unsigned short* __restrict__ in, unsigned short* __restrict__ out,
    const int* __restrict__ row_ptr, const int2* __restrict__ csr, int n) {
  int node = (int)((blockIdx.x * blockDim.x + threadIdx.x) >> 6);
  int lane = threadIdx.x & 63;
  if (node >= n) return;
  int beg = row_ptr[node], end = row_ptr[node + 1];
  const int grp = lane >> 4, sub = lane & 15;
  float acc[8] = {0.f, 0.f, 0.f, 0.f, 0.f, 0.f, 0.f, 0.f};
  for (int j = beg; j < end; j += 4) {
    int idx = j + grp;
    bool act = idx < end;
    int ic = act ? idx : end - 1;
    int2 e = csr[ic];                 // same addr within 16-lane slot -> broadcast
    float w = act ? __int_as_float(e.y) : 0.f;
    short8v v = *(const short8v*)(in + (size_t)e.x * 512 + sub * 8);
    fma8(acc, w, v);
  }
#pragma unroll
  for (int i = 0; i < 8; ++i) {
    acc[i] += __shfl_xor(acc[i], 16, 64);
    acc[i] += __shfl_xor(acc[i], 32, 64);
  }
  if (grp == 0) {
    uint4 r;
    r.x = (unsigned)f2bf(acc[0]) | ((unsigned)f2bf(acc[1]) << 16);
    r.y = (unsigned)f2bf(acc[2]) | ((unsigned)f2bf(acc[3]) << 16);
    r.z = (unsigned)f2bf(acc[4]) | ((unsigned)f2bf(acc[5]) << 16);
    r.w = (unsigned)f2bf(acc[6]) | ((unsigned)f2bf(acc[7]) << 16);
    *(uint4*)(out + (size_t)node * 512 + sub * 8) = r;
  }
}

// ---------------- GEMM1 (MFMA): H = relu(P[N,512] @ W1 + b1), bf16 out ----------------
__global__ __launch_bounds__(256) void gemm1m_kernel(
    const unsigned short* __restrict__ A,    // [NROWP][512] bf16
    const unsigned short* __restrict__ Bt,   // [128][512] bf16 (W1 transposed)
    const float* __restrict__ bias,
    unsigned short* __restrict__ H) {        // [NROWP][128] bf16
  __shared__ short As[64 * 32];
  __shared__ short Bs[128 * 32];
  const int tid = threadIdx.x;
  const int lane = tid & 63;
  const int w = tid >> 6;
  const int wr = w & 1;
  const int wc = w >> 1;
  const int row0 = blockIdx.x * 64;
  f32x4 acc[2][4];
#pragma unroll
  for (int i = 0; i < 2; ++i)
#pragma unroll
    for (int j = 0; j < 4; ++j) acc[i][j] = (f32x4)0.f;

  const int lrow = lane >> 2;
  const int lkp = lane & 3;

  for (int k0 = 0; k0 < 512; k0 += 32) {
    gload_lds16(A + (size_t)(row0 + w * 16 + lrow) * 512 + k0 + lkp * 8, &As[w * 512]);
    gload_lds16(Bt + (size_t)(w * 16 + lrow) * 512 + k0 + lkp * 8, &Bs[w * 512]);
    gload_lds16(Bt + (size_t)((w + 4) * 16 + lrow) * 512 + k0 + lkp * 8, &Bs[(w + 4) * 512]);
    __syncthreads();
    const int kg = lane >> 4, rr = lane & 15;
    bf16x8 af[2], bfr[4];
#pragma unroll
    for (int mr = 0; mr < 2; ++mr)
      af[mr] = __builtin_bit_cast(bf16x8,
          *(const short8v*)&As[(wr * 32 + mr * 16 + rr) * 32 + kg * 8]);
#pragma unroll
    for (int nr = 0; nr < 4; ++nr)
      bfr[nr] = __builtin_bit_cast(bf16x8,
          *(const short8v*)&Bs[(wc * 64 + nr * 16 + rr) * 32 + kg * 8]);
#pragma unroll
    for (int mr = 0; mr < 2; ++mr)
#pragma unroll
      for (int nr = 0; nr < 4; ++nr)
        acc[mr][nr] = mfma_bf16(af[mr], bfr[nr], acc[mr][nr]);
    __syncthreads();
  }
  const int cg = lane >> 4, cl = lane & 15;
#pragma unroll
  for (int mr = 0; mr < 2; ++mr)
#pragma unroll
    for (int nr = 0; nr < 4; ++nr) {
      int col = wc * 64 + nr * 16 + cl;
      float bv = bias[col];
#pragma unroll
      for (int j = 0; j < 4; ++j) {
        int row = row0 + wr * 32 + mr * 16 + cg * 4 + j;
        H[(size_t)row * 128 + col] = f2bf(fmaxf(acc[mr][nr][j] + bv, 0.f));
      }
    }
}

// ---------------- GEMM2 (MFMA): Gk[N,64-padded] bf16, k=0..3 ----------------
__global__ __launch_bounds__(256) void gemm2m_kernel(
    const unsigned short* __restrict__ A,    // [NROWP][128] bf16
    const unsigned short* __restrict__ Bt,   // [160][128] bf16
    unsigned short* __restrict__ G) {        // 4 x [NROWP][64] bf16 (cols 40..63 pad)
  __shared__ short As[64 * 32];
  __shared__ short Bs[160 * 32];
  const int tid = threadIdx.x;
  const int lane = tid & 63;
  const int w = tid >> 6;
  const int row0 = blockIdx.x * 64;
  f32x4 acc[10];
#pragma unroll
  for (int i = 0; i < 10; ++i) acc[i] = (f32x4)0.f;
  const int lrow = lane >> 2, lkp = lane & 3;

  for (int k0 = 0; k0 < 128; k0 += 32) {
    gload_lds16(A + (size_t)(row0 + w * 16 + lrow) * 128 + k0 + lkp * 8, &As[w * 512]);
    for (int c = w; c < 10; c += 4)
      gload_lds16(Bt + (size_t)(c * 16 + lrow) * 128 + k0 + lkp * 8, &Bs[c * 512]);
    __syncthreads();
    const int kg = lane >> 4, rr = lane & 15;
    bf16x8 af = __builtin_bit_cast(bf16x8,
        *(const short8v*)&As[(w * 16 + rr) * 32 + kg * 8]);
#pragma unroll
    for (int nr = 0; nr < 10; ++nr) {
      bf16x8 bfr = __builtin_bit_cast(bf16x8,
          *(const short8v*)&Bs[(nr * 16 + rr) * 32 + kg * 8]);
      acc[nr] = mfma_bf16(af, bfr, acc[nr]);
    }
    __syncthreads();
  }
  const int cg = lane >> 4, cl = lane & 15;
#pragma unroll
  for (int nr = 0; nr < 10; ++nr) {
    int col = nr * 16 + cl;      // 0..159
    int k = col / 40;            // hop block
    int o = col - k * 40;
#pragma unroll
    for (int j = 0; j < 4; ++j) {
      int row = row0 + w * 16 + cg * 4 + j;
      G[(size_t)k * NROWP * 64 + (size_t)row * 64 + o] = f2bf(acc[nr][j]);
    }
  }
}

// ---------------- 40(64-pad)-dim propagation: 8 slots x 8 lanes, 16B loads ----------------
__global__ __launch_bounds__(256) void prop40d_kernel(
    const unsigned short* __restrict__ in,   // [n][64] bf16 (pad cols garbage-ok)
    const unsigned short* __restrict__ add,  // [n][64]
    unsigned short* __restrict__ out,        // [n][64]
    const int* __restrict__ row_ptr, const int2* __restrict__ csr, int n) {
  int node = (int)((blockIdx.x * blockDim.x + threadIdx.x) >> 6);
  int lane = threadIdx.x & 63;
  if (node >= n) return;
  int beg = row_ptr[node], end = row_ptr[node + 1];
  const int grp = lane >> 3, sub = lane & 7;
  float acc[8] = {0.f, 0.f, 0.f, 0.f, 0.f, 0.f, 0.f, 0.f};
  if (grp == 0) {
    short8v a = *(const short8v*)(add + (size_t)node * 64 + sub * 8);
    fma8(acc, 1.0f, a);
  }
  for (int j = beg; j < end; j += 8) {
    int idx = j + grp;
    bool act = idx < end;
    int ic = act ? idx : end - 1;
    int2 e = csr[ic];                 // same addr within 8-lane slot -> broadcast
    float w = act ? __int_as_float(e.y) : 0.f;
    short8v v = *(const short8v*)(in + (size_t)e.x * 64 + sub * 8);
    fma8(acc, w, v);
  }
#pragma unroll
  for (int i = 0; i < 8; ++i) {
    acc[i] += __shfl_xor(acc[i], 8, 64);
    acc[i] += __shfl_xor(acc[i], 16, 64);
    acc[i] += __shfl_xor(acc[i], 32, 64);
  }
  if (grp == 0) {
    uint4 r;
    r.x = (unsigned)f2bf(acc[0]) | ((unsigned)f2bf(acc[1]) << 16);
    r.y = (unsigned)f2bf(acc[2]) | ((unsigned)f2bf(acc[3]) << 16);
    r.z = (unsigned)f2bf(acc[4]) | ((unsigned)f2bf(acc[5]) << 16);
    r.w = (unsigned)f2bf(acc[6]) | ((unsigned)f2bf(acc[7]) << 16);
    *(uint4*)(out + (size_t)node * 64 + sub * 8) = r;
  }
}

// ---------------- final hop fused with bias + log_softmax ----------------
__global__ __launch_bounds__(256) void prop40d_lsm_kernel(
    const unsigned short* __restrict__ in,   // [n][64]
    const unsigned short* __restrict__ add,  // [n][64]
    const float* __restrict__ b2,
    float* __restrict__ out,                 // [n][40] f32
    const int* __restrict__ row_ptr, const int2* __restrict__ csr, int n) {
  int node = (int)((blockIdx.x * blockDim.x + threadIdx.x) >> 6);
  int lane = threadIdx.x & 63;
  if (node >= n) return;
  int beg = row_ptr[node], end = row_ptr[node + 1];
  const int grp = lane >> 3, sub = lane & 7;
  float acc[8] = {0.f, 0.f, 0.f, 0.f, 0.f, 0.f, 0.f, 0.f};
  if (grp == 0) {
    short8v a = *(const short8v*)(add + (size_t)node * 64 + sub * 8);
    fma8(acc, 1.0f, a);
  }
  for (int j = beg; j < end; j += 8) {
    int idx = j + grp;
    bool act = idx < end;
    int ic = act ? idx : end - 1;
    int2 e = csr[ic];
    float w = act ? __int_as_float(e.y) : 0.f;
    short8v v = *(const short8v*)(in + (size_t)e.x * 64 + sub * 8);
    fma8(acc, w, v);
  }
#pragma unroll
  for (int i = 0; i < 8; ++i) {
    acc[i] += __shfl_xor(acc[i], 8, 64);
    acc[i] += __shfl_xor(acc[i], 16, 64);
    acc[i] += __shfl_xor(acc[i], 32, 64);
  }
  // every lane holds full sums for cols sub*8 .. sub*8+7
  bool val = (sub < 5);
  float vv[8];
  if (val) {
    float4 b0 = *(const float4*)(b2 + sub * 8);
    float4 b1v = *(const float4*)(b2 + sub * 8 + 4);
    vv[0] = acc[0] + b0.x; vv[1] = acc[1] + b0.y;
    vv[2] = acc[2] + b0.z; vv[3] = acc[3] + b0.w;
    vv[4] = acc[4] + b1v.x; vv[5] = acc[5] + b1v.y;
    vv[6] = acc[6] + b1v.z; vv[7] = acc[7] + b1v.w;
  } else {
#pragma unroll
    for (int i = 0; i < 8; ++i) vv[i] = -__builtin_inff();
  }
  float mx = vv[0];
#pragma unroll
  for (int i = 1; i < 8; ++i) mx = fmaxf(mx, vv[i]);
#pragma unroll
  for (int o = 1; o < 8; o <<= 1) mx = fmaxf(mx, __shfl_xor(mx, o, 64));
  float s = 0.f;
  if (val) {
#pragma unroll
    for (int i = 0; i < 8; ++i) s += expf(vv[i] - mx);
  }
#pragma unroll
  for (int o = 1; o < 8; o <<= 1) s += __shfl_xor(s, o, 64);
  if (grp == 0 && val) {
    float ls = logf(s);
    float4 o0, o1;
    o0.x = vv[0] - mx - ls; o0.y = vv[1] - mx - ls;
    o0.z = vv[2] - mx - ls; o0.w = vv[3] - mx - ls;
    o1.x = vv[4] - mx - ls; o1.y = vv[5] - mx - ls;
    o1.z = vv[6] - mx - ls; o1.w = vv[7] - mx - ls;
    *(float4*)(out + (size_t)node * 40 + sub * 8) = o0;
    *(float4*)(out + (size_t)node * 40 + sub * 8 + 4) = o1;
  }
}

extern "C" void kernel_launch(void* const* d_in, const int* in_sizes, int n_in,
                              void* d_out, int out_size, void* d_ws, size_t ws_size,
                              hipStream_t stream) {
  const float* x  = (const float*)d_in[0];
  const int*   ei = (const int*)d_in[1];
  const float* W1 = (const float*)d_in[2];
  const float* b1 = (const float*)d_in[3];
  const float* W2 = (const float*)d_in[4];
  const float* b2 = (const float*)d_in[5];
  const int* srcv = ei;
  const int* dstv = ei + NEDGES;
  float* out = (float*)d_out;

  char* wsb = (char*)d_ws;
  size_t off = 0;
  auto alloc = [&](size_t bytes) {
    char* p = wsb + off;
    off += (bytes + 255) & ~(size_t)255;
    return p;
  };
  int*            cnt     = (int*)            alloc((size_t)NNODES * 4);
  float*          dis     = (float*)          alloc((size_t)NNODES * 4);
  int*            row_ptr = (int*)            alloc(((size_t)NNODES + 1) * 4);
  int*            bcur    = (int*)            alloc((size_t)256 * 4);
  int*            bsums   = (int*)            alloc((size_t)SCAN_NB * 4);
  int*            boff    = (int*)            alloc((size_t)SCAN_NB * 4);
  int2*           bkt     = (int2*)           alloc((size_t)NBKT * BCAP * 8);
  int2*           csr     = (int2*)           alloc((size_t)NEDGES * 8);
  unsigned short* W1t     = (unsigned short*) alloc((size_t)128 * 512 * 2);
  unsigned short* W2pt    = (unsigned short*) alloc((size_t)160 * 128 * 2);
  unsigned short* P       = (unsigned short*) alloc((size_t)NROWP * 512 * 2);
  unsigned short* H       = (unsigned short*) alloc((size_t)NROWP * 128 * 2);
  unsigned short* G       = (unsigned short*) alloc((size_t)4 * NROWP * 64 * 2);
  unsigned short* tb      = (unsigned short*) alloc((size_t)NNODES * 64 * 2);
  unsigned short* t2      = (unsigned short*) alloc((size_t)NNODES * 64 * 2);

  unsigned short* G0 = G;
  unsigned short* G1 = G + (size_t)1 * NROWP * 64;
  unsigned short* G2 = G + (size_t)2 * NROWP * 64;
  unsigned short* G3 = G + (size_t)3 * NROWP * 64;

  hipMemsetAsync(bcur, 0, 256 * 4, stream);
  bucketA_kernel<<<ABLK, 256, 0, stream>>>(srcv, dstv, bcur, bkt);
  histB_kernel<<<NBKT, 256, 0, stream>>>(bcur, bkt, cnt, NNODES);
  bsum_kernel<<<SCAN_NB, 256, 0, stream>>>(cnt, bsums, NNODES);
  bscan_kernel<<<1, 64, 0, stream>>>(bsums, boff, row_ptr, SCAN_NB, NNODES);
  bfinal_kernel<<<SCAN_NB, 256, 0, stream>>>(cnt, boff, row_ptr, dis, NNODES);
  scatB_kernel<<<NBKT, 256, 0, stream>>>(bcur, bkt, row_ptr, dis, csr, NNODES);
  wprep_kernel<<<(512 * 128 + 160 * 128 + 255) / 256, 256, 0, stream>>>(W1, W2, W1t, W2pt);
  copyx_kernel<<<((NNODES * 32) + 255) / 256, 256, 0, stream>>>(x, P, NNODES);

  const int prop_blocks = (NNODES * 64 + 255) / 256;
  // Layer 1: P blocks k = A_hat^k x  (bf16, row stride 512)
  for (int k = 1; k <= KHOP; ++k)
    prop128c_kernel<<<prop_blocks, 256, 0, stream>>>(P + 128 * (k - 1), P + 128 * k,
                                                     row_ptr, csr, NNODES);
  const int gemm_blocks = (NNODES + 63) / 64;  // 784; rows < NROWP
  gemm1m_kernel<<<gemm_blocks, 256, 0, stream>>>(P, W1t, b1, H);
  gemm2m_kernel<<<gemm_blocks, 256, 0, stream>>>(H, W2pt, G);
  // Horner (bf16 storage, fp32 accum): tb = A*G3 + G2 ; t2 = A*tb + G1 ; out = lsm(A*t2 + G0 + b2)
  prop40d_kernel<<<prop_blocks, 256, 0, stream>>>(G3, G2, tb, row_ptr, csr, NNODES);
  prop40d_kernel<<<prop_blocks, 256, 0, stream>>>(tb, G1, t2, row_ptr, csr, NNODES);
  prop40d_lsm_kernel<<<prop_blocks, 256, 0, stream>>>(t2, G0, b2, out, row_ptr, csr, NNODES);
}

// Round 10
// 236.143 us; speedup vs baseline: 1.4090x; 1.1378x over previous
//
#include <hip/hip_runtime.h>
#include <hip/hip_bf16.h>

#define NNODES 50000
#define NROWP  50176   // padded row count (multiple of 64) for GEMM tiles
#define NEDGES 800000
#define KHOP 3
#define SCAN_NB 49     // ceil(NNODES / 1024)
#define NBKT 196       // ceil(50176/256) buckets of 256 nodes
#define BCAP 6144      // entries per bucket (mean 4082, sd ~64 -> safe)
#define ABLK 400       // pass-A blocks
#define ACH  2000      // edges per pass-A block

typedef __attribute__((ext_vector_type(8))) short short8v;
typedef __attribute__((ext_vector_type(8))) __bf16 bf16x8;
typedef __attribute__((ext_vector_type(4))) float f32x4;

__device__ inline unsigned short f2bf(float f) {
  unsigned u = __builtin_bit_cast(unsigned, f);
  u += 0x7fffu + ((u >> 16) & 1u);   // RNE
  return (unsigned short)(u >> 16);
}
__device__ inline float bflo(unsigned u) { return __builtin_bit_cast(float, u << 16); }
__device__ inline float bfhi(unsigned u) { return __builtin_bit_cast(float, u & 0xffff0000u); }

__device__ inline void gload_lds16(const void* g, void* l) {
  __builtin_amdgcn_global_load_lds(
      (const __attribute__((address_space(1))) unsigned int*)g,
      (__attribute__((address_space(3))) unsigned int*)l, 16, 0, 0);
}

__device__ inline f32x4 mfma_bf16(bf16x8 a, bf16x8 b, f32x4 c) {
  return __builtin_amdgcn_mfma_f32_16x16x32_bf16(a, b, c, 0, 0, 0);
}

__device__ inline void fma8(float* acc, float w, short8v v) {
  uint4 u = __builtin_bit_cast(uint4, v);
  acc[0] = fmaf(w, bflo(u.x), acc[0]);
  acc[1] = fmaf(w, bfhi(u.x), acc[1]);
  acc[2] = fmaf(w, bflo(u.y), acc[2]);
  acc[3] = fmaf(w, bfhi(u.y), acc[3]);
  acc[4] = fmaf(w, bflo(u.z), acc[4]);
  acc[5] = fmaf(w, bfhi(u.z), acc[5]);
  acc[6] = fmaf(w, bflo(u.w), acc[6]);
  acc[7] = fmaf(w, bfhi(u.w), acc[7]);
}

__device__ inline void fma4(float* acc, float w, uint2 v) {
  acc[0] = fmaf(w, bflo(v.x), acc[0]);
  acc[1] = fmaf(w, bfhi(v.x), acc[1]);
  acc[2] = fmaf(w, bflo(v.y), acc[2]);
  acc[3] = fmaf(w, bfhi(v.y), acc[3]);
}

// ---------------- Pass A: bucket edges by dst>>8 ----------------
__global__ __launch_bounds__(256) void bucketA_kernel(
    const int* __restrict__ src, const int* __restrict__ dst,
    int* __restrict__ bcur, int2* __restrict__ bkt) {
  __shared__ int2 eb[ACH];
  __shared__ int hist[256];
  __shared__ int base[256];
  int tid = threadIdx.x;
  int e0 = blockIdx.x * ACH;
  int cnt = NEDGES - e0; if (cnt > ACH) cnt = ACH;
  hist[tid] = 0;
  __syncthreads();
  for (int i = tid; i < cnt; i += 256) {
    int s = src[e0 + i], d = dst[e0 + i];
    eb[i] = make_int2(s, d);
    atomicAdd(&hist[d >> 8], 1);
  }
  __syncthreads();
  base[tid] = atomicAdd(&bcur[tid], hist[tid]);
  hist[tid] = 0;
  __syncthreads();
  for (int i = tid; i < cnt; i += 256) {
    int2 e = eb[i];
    int b = e.y >> 8;
    int off = atomicAdd(&hist[b], 1);
    bkt[(size_t)b * BCAP + base[b] + off] = e;
  }
}

// ---------------- per-bucket node histogram ----------------
__global__ __launch_bounds__(256) void histB_kernel(
    const int* __restrict__ bcur, const int2* __restrict__ bkt,
    int* __restrict__ cnt, int n) {
  __shared__ int h[256];
  int b = blockIdx.x, tid = threadIdx.x;
  h[tid] = 0;
  __syncthreads();
  int sz = bcur[b];
  for (int i = tid; i < sz; i += 256)
    atomicAdd(&h[bkt[(size_t)b * BCAP + i].y & 255], 1);
  __syncthreads();
  int node = b * 256 + tid;
  if (node < n) cnt[node] = h[tid];
}

// --- hierarchical exclusive scan: bsum -> bscan -> bfinal (+dis fused) ---
__global__ __launch_bounds__(256) void bsum_kernel(const int* __restrict__ cnt,
                                                   int* __restrict__ bsums, int n) {
  __shared__ int sd[256];
  int tid = threadIdx.x;
  int base = blockIdx.x * 1024 + tid * 4;
  int s = 0;
  if (base + 4 <= n) {
    int4 v = *(const int4*)&cnt[base];
    s = v.x + v.y + v.z + v.w;
  }
  sd[tid] = s;
  __syncthreads();
  for (int o = 128; o; o >>= 1) {
    if (tid < o) sd[tid] += sd[tid + o];
    __syncthreads();
  }
  if (tid == 0) bsums[blockIdx.x] = sd[0];
}

__global__ __launch_bounds__(64) void bscan_kernel(const int* __restrict__ bsums,
                                                   int* __restrict__ boff,
                                                   int* __restrict__ row_ptr,
                                                   int nb, int n) {
  int tid = threadIdx.x;
  int own = (tid < nb) ? bsums[tid] : 0;
  int v = own;
#pragma unroll
  for (int o = 1; o < 64; o <<= 1) {
    int t = __shfl_up(v, o, 64);
    if (tid >= o) v += t;
  }
  if (tid < nb) boff[tid] = v - own;   // exclusive block offset
  if (tid == 63) row_ptr[n] = v;       // total edge count
}

__global__ __launch_bounds__(256) void bfinal_kernel(const int* __restrict__ cnt,
                                                     const int* __restrict__ boff,
                                                     int* __restrict__ row_ptr,
                                                     float* __restrict__ dis, int n) {
  __shared__ int sd[256];
  int tid = threadIdx.x;
  int base = blockIdx.x * 1024 + tid * 4;
  int4 v = make_int4(0, 0, 0, 0);
  bool ok = (base + 4 <= n);
  if (ok) v = *(const int4*)&cnt[base];
  int s = v.x + v.y + v.z + v.w;
  sd[tid] = s;
  __syncthreads();
  for (int o = 1; o < 256; o <<= 1) {
    int t = (tid >= o) ? sd[tid - o] : 0;
    __syncthreads();
    sd[tid] += t;
    __syncthreads();
  }
  if (ok) {
    int run = boff[blockIdx.x] + sd[tid] - s;  // exclusive prefix
    int4 rp;
    rp.x = run;
    rp.y = run + v.x;
    rp.z = rp.y + v.y;
    rp.w = rp.z + v.z;
    *(int4*)&row_ptr[base] = rp;
    float4 dv;
    dv.x = (v.x > 0) ? rsqrtf((float)v.x) : 0.f;
    dv.y = (v.y > 0) ? rsqrtf((float)v.y) : 0.f;
    dv.z = (v.z > 0) ? rsqrtf((float)v.z) : 0.f;
    dv.w = (v.w > 0) ? rsqrtf((float)v.w) : 0.f;
    *(float4*)&dis[base] = dv;
  }
}

// ---------------- Pass B: per-bucket scatter into CSR ----------------
__global__ __launch_bounds__(256) void scatB_kernel(
    const int* __restrict__ bcur, const int2* __restrict__ bkt,
    const int* __restrict__ row_ptr, const float* __restrict__ dis,
    int2* __restrict__ csr, int n) {
  __shared__ int cur[256];
  int b = blockIdx.x, tid = threadIdx.x;
  int node = b * 256 + tid;
  cur[tid] = (node < n) ? row_ptr[node] : 0;
  __syncthreads();
  int sz = bcur[b];
  for (int i = tid; i < sz; i += 256) {
    int2 e = bkt[(size_t)b * BCAP + i];
    int pos = atomicAdd(&cur[e.y & 255], 1);
    int2 ent;
    ent.x = e.x;
    ent.y = __float_as_int(dis[e.x] * dis[e.y]);
    csr[pos] = ent;
  }
}

// ---------------- fused weight transforms ----------------
__global__ void wprep_kernel(const float* __restrict__ W1, const float* __restrict__ W2,
                             unsigned short* __restrict__ W1t,
                             unsigned short* __restrict__ W2pt) {
  int t = blockIdx.x * blockDim.x + threadIdx.x;
  if (t < 512 * 128) {
    int c = t >> 9, k = t & 511;
    W1t[t] = f2bf(W1[(size_t)k * 128 + c]);
  } else if (t < 512 * 128 + 160 * 128) {
    int u = t - 512 * 128;
    int q = u >> 7, r = u & 127;
    int k = q / 40, c = q - k * 40;
    W2pt[u] = f2bf(W2[(size_t)(k * 128 + r) * 40 + c]);
  }
}

// ---------------- x -> bf16 into P block 0 ----------------
__global__ void copyx_kernel(const float* __restrict__ x, unsigned short* __restrict__ P, int n) {
  int t = blockIdx.x * blockDim.x + threadIdx.x;
  int i = t >> 5;
  int c4 = (t & 31) << 2;
  if (i < n) {
    float4 v = *(const float4*)&x[(size_t)i * 128 + c4];
    unsigned lo = (unsigned)f2bf(v.x) | ((unsigned)f2bf(v.y) << 16);
    unsigned hi = (unsigned)f2bf(v.z) | ((unsigned)f2bf(v.w) << 16);
    uint2 o; o.x = lo; o.y = hi;
    *(uint2*)&P[(size_t)i * 512 + c4] = o;
  }
}

// ---------------- 128-dim bf16 propagation: 4 slots x 16 lanes, 2x-pipelined ----------------
__global__ __launch_bounds__(256) void prop128c_kernel(
    const unsigned short* __restrict__ in, unsigned short* __restrict__ out,
    const int* __restrict__ row_ptr, const int2* __restrict__ csr, int n) {
  int node = (int)((blockIdx.x * blockDim.x + threadIdx.x) >> 6);
  int lane = threadIdx.x & 63;
  if (node >= n) return;
  int beg = row_ptr[node], end = row_ptr[node + 1];
  int deg = end - beg;
  int2 ent = make_int2(0, 0);
  if (lane < deg) ent = csr[beg + lane];
  const int grp = lane >> 4, sub = lane & 15;
  float acc[8] = {0.f, 0.f, 0.f, 0.f, 0.f, 0.f, 0.f, 0.f};
  int m = deg < 64 ? deg : 64;
  int j = 0;
  // main: 8 edges per iteration, two independent 1KB loads in flight
  for (; j + 8 <= m; j += 8) {
    int s0 = __shfl(ent.x, j + grp, 64);
    float w0 = __int_as_float(__shfl(ent.y, j + grp, 64));
    int s1 = __shfl(ent.x, j + 4 + grp, 64);
    float w1 = __int_as_float(__shfl(ent.y, j + 4 + grp, 64));
    short8v v0 = *(const short8v*)(in + (size_t)s0 * 512 + sub * 8);
    short8v v1 = *(const short8v*)(in + (size_t)s1 * 512 + sub * 8);
    fma8(acc, w0, v0);
    fma8(acc, w1, v1);
  }
  for (; j < m; j += 4) {
    int idx = j + grp;
    bool act = idx < m;
    int ic = act ? idx : m - 1;
    int s0 = __shfl(ent.x, ic, 64);
    float w0 = __int_as_float(__shfl(ent.y, ic, 64));
    if (!act) w0 = 0.f;
    short8v v0 = *(const short8v*)(in + (size_t)s0 * 512 + sub * 8);
    fma8(acc, w0, v0);
  }
  // rare tail: deg > 64 (slot 0 only contributes)
  for (int t = beg + 64; t < end; ++t) {
    int2 e0 = csr[t];
    float w0 = (grp == 0) ? __int_as_float(e0.y) : 0.f;
    short8v v = *(const short8v*)(in + (size_t)e0.x * 512 + sub * 8);
    fma8(acc, w0, v);
  }
#pragma unroll
  for (int i = 0; i < 8; ++i) {
    acc[i] += __shfl_xor(acc[i], 16, 64);
    acc[i] += __shfl_xor(acc[i], 32, 64);
  }
  if (grp == 0) {
    uint4 r;
    r.x = (unsigned)f2bf(acc[0]) | ((unsigned)f2bf(acc[1]) << 16);
    r.y = (unsigned)f2bf(acc[2]) | ((unsigned)f2bf(acc[3]) << 16);
    r.z = (unsigned)f2bf(acc[4]) | ((unsigned)f2bf(acc[5]) << 16);
    r.w = (unsigned)f2bf(acc[6]) | ((unsigned)f2bf(acc[7]) << 16);
    *(uint4*)(out + (size_t)node * 512 + sub * 8) = r;
  }
}

// ---------------- GEMM1 (MFMA): H = relu(P[N,512] @ W1 + b1), bf16 out ----------------
__global__ __launch_bounds__(256) void gemm1m_kernel(
    const unsigned short* __restrict__ A,    // [NROWP][512] bf16
    const unsigned short* __restrict__ Bt,   // [128][512] bf16 (W1 transposed)
    const float* __restrict__ bias,
    unsigned short* __restrict__ H) {        // [NROWP][128] bf16
  __shared__ short As[64 * 32];
  __shared__ short Bs[128 * 32];
  const int tid = threadIdx.x;
  const int lane = tid & 63;
  const int w = tid >> 6;
  const int wr = w & 1;
  const int wc = w >> 1;
  const int row0 = blockIdx.x * 64;
  f32x4 acc[2][4];
#pragma unroll
  for (int i = 0; i < 2; ++i)
#pragma unroll
    for (int j = 0; j < 4; ++j) acc[i][j] = (f32x4)0.f;

  const int lrow = lane >> 2;
  const int lkp = lane & 3;

  for (int k0 = 0; k0 < 512; k0 += 32) {
    gload_lds16(A + (size_t)(row0 + w * 16 + lrow) * 512 + k0 + lkp * 8, &As[w * 512]);
    gload_lds16(Bt + (size_t)(w * 16 + lrow) * 512 + k0 + lkp * 8, &Bs[w * 512]);
    gload_lds16(Bt + (size_t)((w + 4) * 16 + lrow) * 512 + k0 + lkp * 8, &Bs[(w + 4) * 512]);
    __syncthreads();
    const int kg = lane >> 4, rr = lane & 15;
    bf16x8 af[2], bfr[4];
#pragma unroll
    for (int mr = 0; mr < 2; ++mr)
      af[mr] = __builtin_bit_cast(bf16x8,
          *(const short8v*)&As[(wr * 32 + mr * 16 + rr) * 32 + kg * 8]);
#pragma unroll
    for (int nr = 0; nr < 4; ++nr)
      bfr[nr] = __builtin_bit_cast(bf16x8,
          *(const short8v*)&Bs[(wc * 64 + nr * 16 + rr) * 32 + kg * 8]);
#pragma unroll
    for (int mr = 0; mr < 2; ++mr)
#pragma unroll
      for (int nr = 0; nr < 4; ++nr)
        acc[mr][nr] = mfma_bf16(af[mr], bfr[nr], acc[mr][nr]);
    __syncthreads();
  }
  const int cg = lane >> 4, cl = lane & 15;
#pragma unroll
  for (int mr = 0; mr < 2; ++mr)
#pragma unroll
    for (int nr = 0; nr < 4; ++nr) {
      int col = wc * 64 + nr * 16 + cl;
      float bv = bias[col];
#pragma unroll
      for (int j = 0; j < 4; ++j) {
        int row = row0 + wr * 32 + mr * 16 + cg * 4 + j;
        H[(size_t)row * 128 + col] = f2bf(fmaxf(acc[mr][nr][j] + bv, 0.f));
      }
    }
}

// ---------------- GEMM2 (MFMA): Gk[N,64-padded] bf16, k=0..3 ----------------
__global__ __launch_bounds__(256) void gemm2m_kernel(
    const unsigned short* __restrict__ A,    // [NROWP][128] bf16
    const unsigned short* __restrict__ Bt,   // [160][128] bf16
    unsigned short* __restrict__ G) {        // 4 x [NROWP][64] bf16 (cols 40..63 pad)
  __shared__ short As[64 * 32];
  __shared__ short Bs[160 * 32];
  const int tid = threadIdx.x;
  const int lane = tid & 63;
  const int w = tid >> 6;
  const int row0 = blockIdx.x * 64;
  f32x4 acc[10];
#pragma unroll
  for (int i = 0; i < 10; ++i) acc[i] = (f32x4)0.f;
  const int lrow = lane >> 2, lkp = lane & 3;

  for (int k0 = 0; k0 < 128; k0 += 32) {
    gload_lds16(A + (size_t)(row0 + w * 16 + lrow) * 128 + k0 + lkp * 8, &As[w * 512]);
    for (int c = w; c < 10; c += 4)
      gload_lds16(Bt + (size_t)(c * 16 + lrow) * 128 + k0 + lkp * 8, &Bs[c * 512]);
    __syncthreads();
    const int kg = lane >> 4, rr = lane & 15;
    bf16x8 af = __builtin_bit_cast(bf16x8,
        *(const short8v*)&As[(w * 16 + rr) * 32 + kg * 8]);
#pragma unroll
    for (int nr = 0; nr < 10; ++nr) {
      bf16x8 bfr = __builtin_bit_cast(bf16x8,
          *(const short8v*)&Bs[(nr * 16 + rr) * 32 + kg * 8]);
      acc[nr] = mfma_bf16(af, bfr, acc[nr]);
    }
    __syncthreads();
  }
  const int cg = lane >> 4, cl = lane & 15;
#pragma unroll
  for (int nr = 0; nr < 10; ++nr) {
    int col = nr * 16 + cl;      // 0..159
    int k = col / 40;            // hop block
    int o = col - k * 40;
#pragma unroll
    for (int j = 0; j < 4; ++j) {
      int row = row0 + w * 16 + cg * 4 + j;
      G[(size_t)k * NROWP * 64 + (size_t)row * 64 + o] = f2bf(acc[nr][j]);
    }
  }
}

// ---------------- 40(64-pad)-dim propagation: 4 slots x 16 lanes, 2x-pipelined ----------------
__global__ __launch_bounds__(256) void prop40c_kernel(
    const unsigned short* __restrict__ in,   // [n][64] bf16 (pad cols garbage-ok)
    const unsigned short* __restrict__ add,  // [n][64]
    unsigned short* __restrict__ out,        // [n][64]
    const int* __restrict__ row_ptr, const int2* __restrict__ csr, int n) {
  int node = (int)((blockIdx.x * blockDim.x + threadIdx.x) >> 6);
  int lane = threadIdx.x & 63;
  if (node >= n) return;
  int beg = row_ptr[node], end = row_ptr[node + 1];
  int deg = end - beg;
  int2 ent = make_int2(0, 0);
  if (lane < deg) ent = csr[beg + lane];
  const int grp = lane >> 4, sub = lane & 15;
  float acc[4] = {0.f, 0.f, 0.f, 0.f};
  if (grp == 0) {
    uint2 a = *(const uint2*)(add + (size_t)node * 64 + sub * 4);
    acc[0] = bflo(a.x); acc[1] = bfhi(a.x);
    acc[2] = bflo(a.y); acc[3] = bfhi(a.y);
  }
  int m = deg < 64 ? deg : 64;
  int j = 0;
  for (; j + 8 <= m; j += 8) {
    int s0 = __shfl(ent.x, j + grp, 64);
    float w0 = __int_as_float(__shfl(ent.y, j + grp, 64));
    int s1 = __shfl(ent.x, j + 4 + grp, 64);
    float w1 = __int_as_float(__shfl(ent.y, j + 4 + grp, 64));
    uint2 v0 = *(const uint2*)(in + (size_t)s0 * 64 + sub * 4);
    uint2 v1 = *(const uint2*)(in + (size_t)s1 * 64 + sub * 4);
    fma4(acc, w0, v0);
    fma4(acc, w1, v1);
  }
  for (; j < m; j += 4) {
    int idx = j + grp;
    bool act = idx < m;
    int ic = act ? idx : m - 1;
    int s0 = __shfl(ent.x, ic, 64);
    float w0 = __int_as_float(__shfl(ent.y, ic, 64));
    if (!act) w0 = 0.f;
    uint2 v0 = *(const uint2*)(in + (size_t)s0 * 64 + sub * 4);
    fma4(acc, w0, v0);
  }
  for (int t = beg + 64; t < end; ++t) {
    int2 e0 = csr[t];
    float w = (grp == 0) ? __int_as_float(e0.y) : 0.f;
    uint2 v = *(const uint2*)(in + (size_t)e0.x * 64 + sub * 4);
    fma4(acc, w, v);
  }
#pragma unroll
  for (int i = 0; i < 4; ++i) {
    acc[i] += __shfl_xor(acc[i], 16, 64);
    acc[i] += __shfl_xor(acc[i], 32, 64);
  }
  if (grp == 0) {
    uint2 r;
    r.x = (unsigned)f2bf(acc[0]) | ((unsigned)f2bf(acc[1]) << 16);
    r.y = (unsigned)f2bf(acc[2]) | ((unsigned)f2bf(acc[3]) << 16);
    *(uint2*)(out + (size_t)node * 64 + sub * 4) = r;
  }
}

// ---------------- final hop fused with bias + log_softmax ----------------
__global__ __launch_bounds__(256) void prop40c_lsm_kernel(
    const unsigned short* __restrict__ in,   // [n][64]
    const unsigned short* __restrict__ add,  // [n][64]
    const float* __restrict__ b2,
    float* __restrict__ out,                 // [n][40] f32
    const int* __restrict__ row_ptr, const int2* __restrict__ csr, int n) {
  int node = (int)((blockIdx.x * blockDim.x + threadIdx.x) >> 6);
  int lane = threadIdx.x & 63;
  if (node >= n) return;
  int beg = row_ptr[node], end = row_ptr[node + 1];
  int deg = end - beg;
  int2 ent = make_int2(0, 0);
  if (lane < deg) ent = csr[beg + lane];
  const int grp = lane >> 4, sub = lane & 15;
  float acc[4] = {0.f, 0.f, 0.f, 0.f};
  if (grp == 0) {
    uint2 a = *(const uint2*)(add + (size_t)node * 64 + sub * 4);
    acc[0] = bflo(a.x); acc[1] = bfhi(a.x);
    acc[2] = bflo(a.y); acc[3] = bfhi(a.y);
  }
  int m = deg < 64 ? deg : 64;
  int j = 0;
  for (; j + 8 <= m; j += 8) {
    int s0 = __shfl(ent.x, j + grp, 64);
    float w0 = __int_as_float(__shfl(ent.y, j + grp, 64));
    int s1 = __shfl(ent.x, j + 4 + grp, 64);
    float w1 = __int_as_float(__shfl(ent.y, j + 4 + grp, 64));
    uint2 v0 = *(const uint2*)(in + (size_t)s0 * 64 + sub * 4);
    uint2 v1 = *(const uint2*)(in + (size_t)s1 * 64 + sub * 4);
    fma4(acc, w0, v0);
    fma4(acc, w1, v1);
  }
  for (; j < m; j += 4) {
    int idx = j + grp;
    bool act = idx < m;
    int ic = act ? idx : m - 1;
    int s0 = __shfl(ent.x, ic, 64);
    float w0 = __int_as_float(__shfl(ent.y, ic, 64));
    if (!act) w0 = 0.f;
    uint2 v0 = *(const uint2*)(in + (size_t)s0 * 64 + sub * 4);
    fma4(acc, w0, v0);
  }
  for (int t = beg + 64; t < end; ++t) {
    int2 e0 = csr[t];
    float w = (grp == 0) ? __int_as_float(e0.y) : 0.f;
    uint2 v = *(const uint2*)(in + (size_t)e0.x * 64 + sub * 4);
    fma4(acc, w, v);
  }
#pragma unroll
  for (int i = 0; i < 4; ++i) {
    acc[i] += __shfl_xor(acc[i], 16, 64);
    acc[i] += __shfl_xor(acc[i], 32, 64);
  }
  // every lane now holds the full sums for cols sub*4..sub*4+3
  bool val = (sub < 10);
  float vv[4];
  if (val) {
    float4 bv = *(const float4*)(b2 + sub * 4);
    vv[0] = acc[0] + bv.x; vv[1] = acc[1] + bv.y;
    vv[2] = acc[2] + bv.z; vv[3] = acc[3] + bv.w;
  } else {
    vv[0] = vv[1] = vv[2] = vv[3] = -__builtin_inff();
  }
  float mx = fmaxf(fmaxf(vv[0], vv[1]), fmaxf(vv[2], vv[3]));
#pragma unroll
  for (int o = 1; o < 16; o <<= 1) mx = fmaxf(mx, __shfl_xor(mx, o, 64));
  float s = 0.f;
  if (val)
    s = expf(vv[0] - mx) + expf(vv[1] - mx) + expf(vv[2] - mx) + expf(vv[3] - mx);
#pragma unroll
  for (int o = 1; o < 16; o <<= 1) s += __shfl_xor(s, o, 64);
  if (grp == 0 && val) {
    float ls = logf(s);
    float4 o4;
    o4.x = vv[0] - mx - ls; o4.y = vv[1] - mx - ls;
    o4.z = vv[2] - mx - ls; o4.w = vv[3] - mx - ls;
    *(float4*)(out + (size_t)node * 40 + sub * 4) = o4;
  }
}

extern "C" void kernel_launch(void* const* d_in, const int* in_sizes, int n_in,
                              void* d_out, int out_size, void* d_ws, size_t ws_size,
                              hipStream_t stream) {
  const float* x  = (const float*)d_in[0];
  const int*   ei = (const int*)d_in[1];
  const float* W1 = (const float*)d_in[2];
  const float* b1 = (const float*)d_in[3];
  const float* W2 = (const float*)d_in[4];
  const float* b2 = (const float*)d_in[5];
  const int* srcv = ei;
  const int* dstv = ei + NEDGES;
  float* out = (float*)d_out;

  char* wsb = (char*)d_ws;
  size_t off = 0;
  auto alloc = [&](size_t bytes) {
    char* p = wsb + off;
    off += (bytes + 255) & ~(size_t)255;
    return p;
  };
  int*            cnt     = (int*)            alloc((size_t)NNODES * 4);
  float*          dis     = (float*)          alloc((size_t)NNODES * 4);
  int*            row_ptr = (int*)            alloc(((size_t)NNODES + 1) * 4);
  int*            bcur    = (int*)            alloc((size_t)256 * 4);
  int*            bsums   = (int*)            alloc((size_t)SCAN_NB * 4);
  int*            boff    = (int*)            alloc((size_t)SCAN_NB * 4);
  int2*           bkt     = (int2*)           alloc((size_t)NBKT * BCAP * 8);
  int2*           csr     = (int2*)           alloc((size_t)NEDGES * 8);
  unsigned short* W1t     = (unsigned short*) alloc((size_t)128 * 512 * 2);
  unsigned short* W2pt    = (unsigned short*) alloc((size_t)160 * 128 * 2);
  unsigned short* P       = (unsigned short*) alloc((size_t)NROWP * 512 * 2);
  unsigned short* H       = (unsigned short*) alloc((size_t)NROWP * 128 * 2);
  unsigned short* G       = (unsigned short*) alloc((size_t)4 * NROWP * 64 * 2);
  unsigned short* tb      = (unsigned short*) alloc((size_t)NNODES * 64 * 2);
  unsigned short* t2      = (unsigned short*) alloc((size_t)NNODES * 64 * 2);

  unsigned short* G0 = G;
  unsigned short* G1 = G + (size_t)1 * NROWP * 64;
  unsigned short* G2 = G + (size_t)2 * NROWP * 64;
  unsigned short* G3 = G + (size_t)3 * NROWP * 64;

  hipMemsetAsync(bcur, 0, 256 * 4, stream);
  bucketA_kernel<<<ABLK, 256, 0, stream>>>(srcv, dstv, bcur, bkt);
  histB_kernel<<<NBKT, 256, 0, stream>>>(bcur, bkt, cnt, NNODES);
  bsum_kernel<<<SCAN_NB, 256, 0, stream>>>(cnt, bsums, NNODES);
  bscan_kernel<<<1, 64, 0, stream>>>(bsums, boff, row_ptr, SCAN_NB, NNODES);
  bfinal_kernel<<<SCAN_NB, 256, 0, stream>>>(cnt, boff, row_ptr, dis, NNODES);
  scatB_kernel<<<NBKT, 256, 0, stream>>>(bcur, bkt, row_ptr, dis, csr, NNODES);
  wprep_kernel<<<(512 * 128 + 160 * 128 + 255) / 256, 256, 0, stream>>>(W1, W2, W1t, W2pt);
  copyx_kernel<<<((NNODES * 32) + 255) / 256, 256, 0, stream>>>(x, P, NNODES);

  const int prop_blocks = (NNODES * 64 + 255) / 256;
  // Layer 1: P blocks k = A_hat^k x  (bf16, row stride 512)
  for (int k = 1; k <= KHOP; ++k)
    prop128c_kernel<<<prop_blocks, 256, 0, stream>>>(P + 128 * (k - 1), P + 128 * k,
                                                     row_ptr, csr, NNODES);
  const int gemm_blocks = (NNODES + 63) / 64;  // 784; rows < NROWP
  gemm1m_kernel<<<gemm_blocks, 256, 0, stream>>>(P, W1t, b1, H);
  gemm2m_kernel<<<gemm_blocks, 256, 0, stream>>>(H, W2pt, G);
  // Horner (bf16 storage, fp32 accum): tb = A*G3 + G2 ; t2 = A*tb + G1 ; out = lsm(A*t2 + G0 + b2)
  prop40c_kernel<<<prop_blocks, 256, 0, stream>>>(G3, G2, tb, row_ptr, csr, NNODES);
  prop40c_kernel<<<prop_blocks, 256, 0, stream>>>(tb, G1, t2, row_ptr, csr, NNODES);
  prop40c_lsm_kernel<<<prop_blocks, 256, 0, stream>>>(t2, G0, b2, out, row_ptr, csr, NNODES);
}

// Round 11
// 229.858 us; speedup vs baseline: 1.4476x; 1.0273x over previous
//
#include <hip/hip_runtime.h>
#include <hip/hip_bf16.h>

#define NNODES 50000
#define NROWP  50176   // padded row count (multiple of 64) for GEMM tiles
#define NEDGES 800000
#define KHOP 3
#define NBKT 196       // ceil(50176/256) buckets of 256 nodes
#define BCAP 6144      // entries per bucket (mean 4082, sd ~64 -> safe)
#define ABLK 400       // pass-A blocks
#define ACH  2000      // edges per pass-A block

typedef __attribute__((ext_vector_type(8))) short short8v;
typedef __attribute__((ext_vector_type(8))) __bf16 bf16x8;
typedef __attribute__((ext_vector_type(4))) float f32x4;

__device__ inline unsigned short f2bf(float f) {
  unsigned u = __builtin_bit_cast(unsigned, f);
  u += 0x7fffu + ((u >> 16) & 1u);   // RNE
  return (unsigned short)(u >> 16);
}
__device__ inline float bflo(unsigned u) { return __builtin_bit_cast(float, u << 16); }
__device__ inline float bfhi(unsigned u) { return __builtin_bit_cast(float, u & 0xffff0000u); }

__device__ inline void gload_lds16(const void* g, void* l) {
  __builtin_amdgcn_global_load_lds(
      (const __attribute__((address_space(1))) unsigned int*)g,
      (__attribute__((address_space(3))) unsigned int*)l, 16, 0, 0);
}

__device__ inline f32x4 mfma_bf16(bf16x8 a, bf16x8 b, f32x4 c) {
  return __builtin_amdgcn_mfma_f32_16x16x32_bf16(a, b, c, 0, 0, 0);
}

__device__ inline void fma8(float* acc, float w, short8v v) {
  uint4 u = __builtin_bit_cast(uint4, v);
  acc[0] = fmaf(w, bflo(u.x), acc[0]);
  acc[1] = fmaf(w, bfhi(u.x), acc[1]);
  acc[2] = fmaf(w, bflo(u.y), acc[2]);
  acc[3] = fmaf(w, bfhi(u.y), acc[3]);
  acc[4] = fmaf(w, bflo(u.z), acc[4]);
  acc[5] = fmaf(w, bfhi(u.z), acc[5]);
  acc[6] = fmaf(w, bflo(u.w), acc[6]);
  acc[7] = fmaf(w, bfhi(u.w), acc[7]);
}

__device__ inline void fma4(float* acc, float w, uint2 v) {
  acc[0] = fmaf(w, bflo(v.x), acc[0]);
  acc[1] = fmaf(w, bfhi(v.x), acc[1]);
  acc[2] = fmaf(w, bflo(v.y), acc[2]);
  acc[3] = fmaf(w, bfhi(v.y), acc[3]);
}

// ---------------- Pass A: bucket edges by dst>>8 ----------------
__global__ __launch_bounds__(256) void bucketA_kernel(
    const int* __restrict__ src, const int* __restrict__ dst,
    int* __restrict__ bcur, int2* __restrict__ bkt) {
  __shared__ int2 eb[ACH];
  __shared__ int hist[256];
  __shared__ int base[256];
  int tid = threadIdx.x;
  int e0 = blockIdx.x * ACH;
  int cnt = NEDGES - e0; if (cnt > ACH) cnt = ACH;
  hist[tid] = 0;
  __syncthreads();
  for (int i = tid; i < cnt; i += 256) {
    int s = src[e0 + i], d = dst[e0 + i];
    eb[i] = make_int2(s, d);
    atomicAdd(&hist[d >> 8], 1);
  }
  __syncthreads();
  base[tid] = atomicAdd(&bcur[tid], hist[tid]);
  hist[tid] = 0;
  __syncthreads();
  for (int i = tid; i < cnt; i += 256) {
    int2 e = eb[i];
    int b = e.y >> 8;
    int off = atomicAdd(&hist[b], 1);
    bkt[(size_t)b * BCAP + base[b] + off] = e;
  }
}

// ---------------- scan bucket totals -> bucket offsets ----------------
__global__ __launch_bounds__(256) void bktscan_kernel(
    const int* __restrict__ bcur, int* __restrict__ boff, int* __restrict__ row_ptr) {
  __shared__ int sd[256];
  int tid = threadIdx.x;
  int own = (tid < NBKT) ? bcur[tid] : 0;
  sd[tid] = own;
  __syncthreads();
  for (int o = 1; o < 256; o <<= 1) {
    int t = (tid >= o) ? sd[tid - o] : 0;
    __syncthreads();
    sd[tid] += t;
    __syncthreads();
  }
  if (tid < NBKT) boff[tid] = sd[tid] - own;   // exclusive
  if (tid == 255) row_ptr[NNODES] = sd[255];   // total edges
}

// ---------------- per-bucket histogram + intra-bucket scan -> row_ptr, dis ----------------
__global__ __launch_bounds__(256) void histC_kernel(
    const int* __restrict__ bcur, const int2* __restrict__ bkt,
    const int* __restrict__ boff, int* __restrict__ row_ptr,
    float* __restrict__ dis, int n) {
  __shared__ int h[256];
  __shared__ int sc[256];
  int b = blockIdx.x, tid = threadIdx.x;
  h[tid] = 0;
  __syncthreads();
  int sz = bcur[b];
  for (int i = tid; i < sz; i += 256)
    atomicAdd(&h[bkt[(size_t)b * BCAP + i].y & 255], 1);
  __syncthreads();
  int own = h[tid];
  sc[tid] = own;
  __syncthreads();
  for (int o = 1; o < 256; o <<= 1) {
    int t = (tid >= o) ? sc[tid - o] : 0;
    __syncthreads();
    sc[tid] += t;
    __syncthreads();
  }
  int node = b * 256 + tid;
  if (node < n) {
    row_ptr[node] = boff[b] + sc[tid] - own;
    dis[node] = (own > 0) ? rsqrtf((float)own) : 0.f;
  }
}

// ---------------- Pass B: per-bucket scatter into CSR ----------------
__global__ __launch_bounds__(256) void scatB_kernel(
    const int* __restrict__ bcur, const int2* __restrict__ bkt,
    const int* __restrict__ row_ptr, const float* __restrict__ dis,
    int2* __restrict__ csr, int n) {
  __shared__ int cur[256];
  int b = blockIdx.x, tid = threadIdx.x;
  int node = b * 256 + tid;
  cur[tid] = (node < n) ? row_ptr[node] : 0;
  __syncthreads();
  int sz = bcur[b];
  for (int i = tid; i < sz; i += 256) {
    int2 e = bkt[(size_t)b * BCAP + i];
    int pos = atomicAdd(&cur[e.y & 255], 1);
    int2 ent;
    ent.x = e.x;
    ent.y = __float_as_int(dis[e.x] * dis[e.y]);
    csr[pos] = ent;
  }
}

// ---------------- fused weight transforms ----------------
__global__ void wprep_kernel(const float* __restrict__ W1, const float* __restrict__ W2,
                             unsigned short* __restrict__ W1t,
                             unsigned short* __restrict__ W2pt) {
  int t = blockIdx.x * blockDim.x + threadIdx.x;
  if (t < 512 * 128) {
    int c = t >> 9, k = t & 511;
    W1t[t] = f2bf(W1[(size_t)k * 128 + c]);
  } else if (t < 512 * 128 + 160 * 128) {
    int u = t - 512 * 128;
    int q = u >> 7, r = u & 127;
    int k = q / 40, c = q - k * 40;
    W2pt[u] = f2bf(W2[(size_t)(k * 128 + r) * 40 + c]);
  }
}

// ---------------- x -> bf16 into P block 0 ----------------
__global__ void copyx_kernel(const float* __restrict__ x, unsigned short* __restrict__ P, int n) {
  int t = blockIdx.x * blockDim.x + threadIdx.x;
  int i = t >> 5;
  int c4 = (t & 31) << 2;
  if (i < n) {
    float4 v = *(const float4*)&x[(size_t)i * 128 + c4];
    unsigned lo = (unsigned)f2bf(v.x) | ((unsigned)f2bf(v.y) << 16);
    unsigned hi = (unsigned)f2bf(v.z) | ((unsigned)f2bf(v.w) << 16);
    uint2 o; o.x = lo; o.y = hi;
    *(uint2*)&P[(size_t)i * 512 + c4] = o;
  }
}

// ---------------- 128-dim bf16 propagation: 4 slots x 16 lanes, 4x-pipelined ----------------
__global__ __launch_bounds__(256) void prop128c_kernel(
    const unsigned short* __restrict__ in, unsigned short* __restrict__ out,
    const int* __restrict__ row_ptr, const int2* __restrict__ csr, int n) {
  int node = (int)((blockIdx.x * blockDim.x + threadIdx.x) >> 6);
  int lane = threadIdx.x & 63;
  if (node >= n) return;
  int beg = row_ptr[node], end = row_ptr[node + 1];
  int deg = end - beg;
  int2 ent = make_int2(0, 0);
  if (lane < deg) ent = csr[beg + lane];
  const int grp = lane >> 4, sub = lane & 15;
  float acc[8] = {0.f, 0.f, 0.f, 0.f, 0.f, 0.f, 0.f, 0.f};
  int m = deg < 64 ? deg : 64;
  int j = 0;
  // 16 edges per iteration, four independent 1KB loads in flight
  for (; j + 16 <= m; j += 16) {
    int s0 = __shfl(ent.x, j + grp, 64);
    float w0 = __int_as_float(__shfl(ent.y, j + grp, 64));
    int s1 = __shfl(ent.x, j + 4 + grp, 64);
    float w1 = __int_as_float(__shfl(ent.y, j + 4 + grp, 64));
    int s2 = __shfl(ent.x, j + 8 + grp, 64);
    float w2 = __int_as_float(__shfl(ent.y, j + 8 + grp, 64));
    int s3 = __shfl(ent.x, j + 12 + grp, 64);
    float w3 = __int_as_float(__shfl(ent.y, j + 12 + grp, 64));
    short8v v0 = *(const short8v*)(in + (size_t)s0 * 512 + sub * 8);
    short8v v1 = *(const short8v*)(in + (size_t)s1 * 512 + sub * 8);
    short8v v2 = *(const short8v*)(in + (size_t)s2 * 512 + sub * 8);
    short8v v3 = *(const short8v*)(in + (size_t)s3 * 512 + sub * 8);
    fma8(acc, w0, v0);
    fma8(acc, w1, v1);
    fma8(acc, w2, v2);
    fma8(acc, w3, v3);
  }
  for (; j + 8 <= m; j += 8) {
    int s0 = __shfl(ent.x, j + grp, 64);
    float w0 = __int_as_float(__shfl(ent.y, j + grp, 64));
    int s1 = __shfl(ent.x, j + 4 + grp, 64);
    float w1 = __int_as_float(__shfl(ent.y, j + 4 + grp, 64));
    short8v v0 = *(const short8v*)(in + (size_t)s0 * 512 + sub * 8);
    short8v v1 = *(const short8v*)(in + (size_t)s1 * 512 + sub * 8);
    fma8(acc, w0, v0);
    fma8(acc, w1, v1);
  }
  for (; j < m; j += 4) {
    int idx = j + grp;
    bool act = idx < m;
    int ic = act ? idx : m - 1;
    int s0 = __shfl(ent.x, ic, 64);
    float w0 = __int_as_float(__shfl(ent.y, ic, 64));
    if (!act) w0 = 0.f;
    short8v v0 = *(const short8v*)(in + (size_t)s0 * 512 + sub * 8);
    fma8(acc, w0, v0);
  }
  // rare tail: deg > 64 (slot 0 only contributes)
  for (int t = beg + 64; t < end; ++t) {
    int2 e0 = csr[t];
    float w0 = (grp == 0) ? __int_as_float(e0.y) : 0.f;
    short8v v = *(const short8v*)(in + (size_t)e0.x * 512 + sub * 8);
    fma8(acc, w0, v);
  }
#pragma unroll
  for (int i = 0; i < 8; ++i) {
    acc[i] += __shfl_xor(acc[i], 16, 64);
    acc[i] += __shfl_xor(acc[i], 32, 64);
  }
  if (grp == 0) {
    uint4 r;
    r.x = (unsigned)f2bf(acc[0]) | ((unsigned)f2bf(acc[1]) << 16);
    r.y = (unsigned)f2bf(acc[2]) | ((unsigned)f2bf(acc[3]) << 16);
    r.z = (unsigned)f2bf(acc[4]) | ((unsigned)f2bf(acc[5]) << 16);
    r.w = (unsigned)f2bf(acc[6]) | ((unsigned)f2bf(acc[7]) << 16);
    *(uint4*)(out + (size_t)node * 512 + sub * 8) = r;
  }
}

// ---------------- GEMM1 (MFMA): H = relu(P[N,512] @ W1 + b1), bf16 out ----------------
__global__ __launch_bounds__(256) void gemm1m_kernel(
    const unsigned short* __restrict__ A,    // [NROWP][512] bf16
    const unsigned short* __restrict__ Bt,   // [128][512] bf16 (W1 transposed)
    const float* __restrict__ bias,
    unsigned short* __restrict__ H) {        // [NROWP][128] bf16
  __shared__ short As[64 * 32];
  __shared__ short Bs[128 * 32];
  const int tid = threadIdx.x;
  const int lane = tid & 63;
  const int w = tid >> 6;
  const int wr = w & 1;
  const int wc = w >> 1;
  const int row0 = blockIdx.x * 64;
  f32x4 acc[2][4];
#pragma unroll
  for (int i = 0; i < 2; ++i)
#pragma unroll
    for (int j = 0; j < 4; ++j) acc[i][j] = (f32x4)0.f;

  const int lrow = lane >> 2;
  const int lkp = lane & 3;

  for (int k0 = 0; k0 < 512; k0 += 32) {
    gload_lds16(A + (size_t)(row0 + w * 16 + lrow) * 512 + k0 + lkp * 8, &As[w * 512]);
    gload_lds16(Bt + (size_t)(w * 16 + lrow) * 512 + k0 + lkp * 8, &Bs[w * 512]);
    gload_lds16(Bt + (size_t)((w + 4) * 16 + lrow) * 512 + k0 + lkp * 8, &Bs[(w + 4) * 512]);
    __syncthreads();
    const int kg = lane >> 4, rr = lane & 15;
    bf16x8 af[2], bfr[4];
#pragma unroll
    for (int mr = 0; mr < 2; ++mr)
      af[mr] = __builtin_bit_cast(bf16x8,
          *(const short8v*)&As[(wr * 32 + mr * 16 + rr) * 32 + kg * 8]);
#pragma unroll
    for (int nr = 0; nr < 4; ++nr)
      bfr[nr] = __builtin_bit_cast(bf16x8,
          *(const short8v*)&Bs[(wc * 64 + nr * 16 + rr) * 32 + kg * 8]);
#pragma unroll
    for (int mr = 0; mr < 2; ++mr)
#pragma unroll
      for (int nr = 0; nr < 4; ++nr)
        acc[mr][nr] = mfma_bf16(af[mr], bfr[nr], acc[mr][nr]);
    __syncthreads();
  }
  const int cg = lane >> 4, cl = lane & 15;
#pragma unroll
  for (int mr = 0; mr < 2; ++mr)
#pragma unroll
    for (int nr = 0; nr < 4; ++nr) {
      int col = wc * 64 + nr * 16 + cl;
      float bv = bias[col];
#pragma unroll
      for (int j = 0; j < 4; ++j) {
        int row = row0 + wr * 32 + mr * 16 + cg * 4 + j;
        H[(size_t)row * 128 + col] = f2bf(fmaxf(acc[mr][nr][j] + bv, 0.f));
      }
    }
}

// ---------------- GEMM2 (MFMA): Gk[N,64-padded] bf16, k=0..3 ----------------
__global__ __launch_bounds__(256) void gemm2m_kernel(
    const unsigned short* __restrict__ A,    // [NROWP][128] bf16
    const unsigned short* __restrict__ Bt,   // [160][128] bf16
    unsigned short* __restrict__ G) {        // 4 x [NROWP][64] bf16 (cols 40..63 pad)
  __shared__ short As[64 * 32];
  __shared__ short Bs[160 * 32];
  const int tid = threadIdx.x;
  const int lane = tid & 63;
  const int w = tid >> 6;
  const int row0 = blockIdx.x * 64;
  f32x4 acc[10];
#pragma unroll
  for (int i = 0; i < 10; ++i) acc[i] = (f32x4)0.f;
  const int lrow = lane >> 2, lkp = lane & 3;

  for (int k0 = 0; k0 < 128; k0 += 32) {
    gload_lds16(A + (size_t)(row0 + w * 16 + lrow) * 128 + k0 + lkp * 8, &As[w * 512]);
    for (int c = w; c < 10; c += 4)
      gload_lds16(Bt + (size_t)(c * 16 + lrow) * 128 + k0 + lkp * 8, &Bs[c * 512]);
    __syncthreads();
    const int kg = lane >> 4, rr = lane & 15;
    bf16x8 af = __builtin_bit_cast(bf16x8,
        *(const short8v*)&As[(w * 16 + rr) * 32 + kg * 8]);
#pragma unroll
    for (int nr = 0; nr < 10; ++nr) {
      bf16x8 bfr = __builtin_bit_cast(bf16x8,
          *(const short8v*)&Bs[(nr * 16 + rr) * 32 + kg * 8]);
      acc[nr] = mfma_bf16(af, bfr, acc[nr]);
    }
    __syncthreads();
  }
  const int cg = lane >> 4, cl = lane & 15;
#pragma unroll
  for (int nr = 0; nr < 10; ++nr) {
    int col = nr * 16 + cl;      // 0..159
    int k = col / 40;            // hop block
    int o = col - k * 40;
#pragma unroll
    for (int j = 0; j < 4; ++j) {
      int row = row0 + w * 16 + cg * 4 + j;
      G[(size_t)k * NROWP * 64 + (size_t)row * 64 + o] = f2bf(acc[nr][j]);
    }
  }
}

// ---------------- 40(64-pad)-dim propagation: 4 slots x 16 lanes, 4x-pipelined ----------------
__global__ __launch_bounds__(256) void prop40c_kernel(
    const unsigned short* __restrict__ in,   // [n][64] bf16 (pad cols garbage-ok)
    const unsigned short* __restrict__ add,  // [n][64]
    unsigned short* __restrict__ out,        // [n][64]
    const int* __restrict__ row_ptr, const int2* __restrict__ csr, int n) {
  int node = (int)((blockIdx.x * blockDim.x + threadIdx.x) >> 6);
  int lane = threadIdx.x & 63;
  if (node >= n) return;
  int beg = row_ptr[node], end = row_ptr[node + 1];
  int deg = end - beg;
  int2 ent = make_int2(0, 0);
  if (lane < deg) ent = csr[beg + lane];
  const int grp = lane >> 4, sub = lane & 15;
  float acc[4] = {0.f, 0.f, 0.f, 0.f};
  if (grp == 0) {
    uint2 a = *(const uint2*)(add + (size_t)node * 64 + sub * 4);
    acc[0] = bflo(a.x); acc[1] = bfhi(a.x);
    acc[2] = bflo(a.y); acc[3] = bfhi(a.y);
  }
  int m = deg < 64 ? deg : 64;
  int j = 0;
  for (; j + 16 <= m; j += 16) {
    int s0 = __shfl(ent.x, j + grp, 64);
    float w0 = __int_as_float(__shfl(ent.y, j + grp, 64));
    int s1 = __shfl(ent.x, j + 4 + grp, 64);
    float w1 = __int_as_float(__shfl(ent.y, j + 4 + grp, 64));
    int s2 = __shfl(ent.x, j + 8 + grp, 64);
    float w2 = __int_as_float(__shfl(ent.y, j + 8 + grp, 64));
    int s3 = __shfl(ent.x, j + 12 + grp, 64);
    float w3 = __int_as_float(__shfl(ent.y, j + 12 + grp, 64));
    uint2 v0 = *(const uint2*)(in + (size_t)s0 * 64 + sub * 4);
    uint2 v1 = *(const uint2*)(in + (size_t)s1 * 64 + sub * 4);
    uint2 v2 = *(const uint2*)(in + (size_t)s2 * 64 + sub * 4);
    uint2 v3 = *(const uint2*)(in + (size_t)s3 * 64 + sub * 4);
    fma4(acc, w0, v0);
    fma4(acc, w1, v1);
    fma4(acc, w2, v2);
    fma4(acc, w3, v3);
  }
  for (; j + 8 <= m; j += 8) {
    int s0 = __shfl(ent.x, j + grp, 64);
    float w0 = __int_as_float(__shfl(ent.y, j + grp, 64));
    int s1 = __shfl(ent.x, j + 4 + grp, 64);
    float w1 = __int_as_float(__shfl(ent.y, j + 4 + grp, 64));
    uint2 v0 = *(const uint2*)(in + (size_t)s0 * 64 + sub * 4);
    uint2 v1 = *(const uint2*)(in + (size_t)s1 * 64 + sub * 4);
    fma4(acc, w0, v0);
    fma4(acc, w1, v1);
  }
  for (; j < m; j += 4) {
    int idx = j + grp;
    bool act = idx < m;
    int ic = act ? idx : m - 1;
    int s0 = __shfl(ent.x, ic, 64);
    float w0 = __int_as_float(__shfl(ent.y, ic, 64));
    if (!act) w0 = 0.f;
    uint2 v0 = *(const uint2*)(in + (size_t)s0 * 64 + sub * 4);
    fma4(acc, w0, v0);
  }
  for (int t = beg + 64; t < end; ++t) {
    int2 e0 = csr[t];
    float w = (grp == 0) ? __int_as_float(e0.y) : 0.f;
    uint2 v = *(const uint2*)(in + (size_t)e0.x * 64 + sub * 4);
    fma4(acc, w, v);
  }
#pragma unroll
  for (int i = 0; i < 4; ++i) {
    acc[i] += __shfl_xor(acc[i], 16, 64);
    acc[i] += __shfl_xor(acc[i], 32, 64);
  }
  if (grp == 0) {
    uint2 r;
    r.x = (unsigned)f2bf(acc[0]) | ((unsigned)f2bf(acc[1]) << 16);
    r.y = (unsigned)f2bf(acc[2]) | ((unsigned)f2bf(acc[3]) << 16);
    *(uint2*)(out + (size_t)node * 64 + sub * 4) = r;
  }
}

// ---------------- final hop fused with bias + log_softmax ----------------
__global__ __launch_bounds__(256) void prop40c_lsm_kernel(
    const unsigned short* __restrict__ in,   // [n][64]
    const unsigned short* __restrict__ add,  // [n][64]
    const float* __restrict__ b2,
    float* __restrict__ out,                 // [n][40] f32
    const int* __restrict__ row_ptr, const int2* __restrict__ csr, int n) {
  int node = (int)((blockIdx.x * blockDim.x + threadIdx.x) >> 6);
  int lane = threadIdx.x & 63;
  if (node >= n) return;
  int beg = row_ptr[node], end = row_ptr[node + 1];
  int deg = end - beg;
  int2 ent = make_int2(0, 0);
  if (lane < deg) ent = csr[beg + lane];
  const int grp = lane >> 4, sub = lane & 15;
  float acc[4] = {0.f, 0.f, 0.f, 0.f};
  if (grp == 0) {
    uint2 a = *(const uint2*)(add + (size_t)node * 64 + sub * 4);
    acc[0] = bflo(a.x); acc[1] = bfhi(a.x);
    acc[2] = bflo(a.y); acc[3] = bfhi(a.y);
  }
  int m = deg < 64 ? deg : 64;
  int j = 0;
  for (; j + 16 <= m; j += 16) {
    int s0 = __shfl(ent.x, j + grp, 64);
    float w0 = __int_as_float(__shfl(ent.y, j + grp, 64));
    int s1 = __shfl(ent.x, j + 4 + grp, 64);
    float w1 = __int_as_float(__shfl(ent.y, j + 4 + grp, 64));
    int s2 = __shfl(ent.x, j + 8 + grp, 64);
    float w2 = __int_as_float(__shfl(ent.y, j + 8 + grp, 64));
    int s3 = __shfl(ent.x, j + 12 + grp, 64);
    float w3 = __int_as_float(__shfl(ent.y, j + 12 + grp, 64));
    uint2 v0 = *(const uint2*)(in + (size_t)s0 * 64 + sub * 4);
    uint2 v1 = *(const uint2*)(in + (size_t)s1 * 64 + sub * 4);
    uint2 v2 = *(const uint2*)(in + (size_t)s2 * 64 + sub * 4);
    uint2 v3 = *(const uint2*)(in + (size_t)s3 * 64 + sub * 4);
    fma4(acc, w0, v0);
    fma4(acc, w1, v1);
    fma4(acc, w2, v2);
    fma4(acc, w3, v3);
  }
  for (; j + 8 <= m; j += 8) {
    int s0 = __shfl(ent.x, j + grp, 64);
    float w0 = __int_as_float(__shfl(ent.y, j + grp, 64));
    int s1 = __shfl(ent.x, j + 4 + grp, 64);
    float w1 = __int_as_float(__shfl(ent.y, j + 4 + grp, 64));
    uint2 v0 = *(const uint2*)(in + (size_t)s0 * 64 + sub * 4);
    uint2 v1 = *(const uint2*)(in + (size_t)s1 * 64 + sub * 4);
    fma4(acc, w0, v0);
    fma4(acc, w1, v1);
  }
  for (; j < m; j += 4) {
    int idx = j + grp;
    bool act = idx < m;
    int ic = act ? idx : m - 1;
    int s0 = __shfl(ent.x, ic, 64);
    float w0 = __int_as_float(__shfl(ent.y, ic, 64));
    if (!act) w0 = 0.f;
    uint2 v0 = *(const uint2*)(in + (size_t)s0 * 64 + sub * 4);
    fma4(acc, w0, v0);
  }
  for (int t = beg + 64; t < end; ++t) {
    int2 e0 = csr[t];
    float w = (grp == 0) ? __int_as_float(e0.y) : 0.f;
    uint2 v = *(const uint2*)(in + (size_t)e0.x * 64 + sub * 4);
    fma4(acc, w, v);
  }
#pragma unroll
  for (int i = 0; i < 4; ++i) {
    acc[i] += __shfl_xor(acc[i], 16, 64);
    acc[i] += __shfl_xor(acc[i], 32, 64);
  }
  // every lane now holds the full sums for cols sub*4..sub*4+3
  bool val = (sub < 10);
  float vv[4];
  if (val) {
    float4 bv = *(const float4*)(b2 + sub * 4);
    vv[0] = acc[0] + bv.x; vv[1] = acc[1] + bv.y;
    vv[2] = acc[2] + bv.z; vv[3] = acc[3] + bv.w;
  } else {
    vv[0] = vv[1] = vv[2] = vv[3] = -__builtin_inff();
  }
  float mx = fmaxf(fmaxf(vv[0], vv[1]), fmaxf(vv[2], vv[3]));
#pragma unroll
  for (int o = 1; o < 16; o <<= 1) mx = fmaxf(mx, __shfl_xor(mx, o, 64));
  float s = 0.f;
  if (val)
    s = expf(vv[0] - mx) + expf(vv[1] - mx) + expf(vv[2] - mx) + expf(vv[3] - mx);
#pragma unroll
  for (int o = 1; o < 16; o <<= 1) s += __shfl_xor(s, o, 64);
  if (grp == 0 && val) {
    float ls = logf(s);
    float4 o4;
    o4.x = vv[0] - mx - ls; o4.y = vv[1] - mx - ls;
    o4.z = vv[2] - mx - ls; o4.w = vv[3] - mx - ls;
    *(float4*)(out + (size_t)node * 40 + sub * 4) = o4;
  }
}

extern "C" void kernel_launch(void* const* d_in, const int* in_sizes, int n_in,
                              void* d_out, int out_size, void* d_ws, size_t ws_size,
                              hipStream_t stream) {
  const float* x  = (const float*)d_in[0];
  const int*   ei = (const int*)d_in[1];
  const float* W1 = (const float*)d_in[2];
  const float* b1 = (const float*)d_in[3];
  const float* W2 = (const float*)d_in[4];
  const float* b2 = (const float*)d_in[5];
  const int* srcv = ei;
  const int* dstv = ei + NEDGES;
  float* out = (float*)d_out;

  char* wsb = (char*)d_ws;
  size_t off = 0;
  auto alloc = [&](size_t bytes) {
    char* p = wsb + off;
    off += (bytes + 255) & ~(size_t)255;
    return p;
  };
  float*          dis     = (float*)          alloc((size_t)NNODES * 4);
  int*            row_ptr = (int*)            alloc(((size_t)NNODES + 1) * 4);
  int*            bcur    = (int*)            alloc((size_t)256 * 4);
  int*            boff    = (int*)            alloc((size_t)NBKT * 4);
  int2*           bkt     = (int2*)           alloc((size_t)NBKT * BCAP * 8);
  int2*           csr     = (int2*)           alloc((size_t)NEDGES * 8);
  unsigned short* W1t     = (unsigned short*) alloc((size_t)128 * 512 * 2);
  unsigned short* W2pt    = (unsigned short*) alloc((size_t)160 * 128 * 2);
  unsigned short* P       = (unsigned short*) alloc((size_t)NROWP * 512 * 2);
  unsigned short* H       = (unsigned short*) alloc((size_t)NROWP * 128 * 2);
  unsigned short* G       = (unsigned short*) alloc((size_t)4 * NROWP * 64 * 2);
  unsigned short* tb      = (unsigned short*) alloc((size_t)NNODES * 64 * 2);
  unsigned short* t2      = (unsigned short*) alloc((size_t)NNODES * 64 * 2);

  unsigned short* G0 = G;
  unsigned short* G1 = G + (size_t)1 * NROWP * 64;
  unsigned short* G2 = G + (size_t)2 * NROWP * 64;
  unsigned short* G3 = G + (size_t)3 * NROWP * 64;

  hipMemsetAsync(bcur, 0, 256 * 4, stream);
  bucketA_kernel<<<ABLK, 256, 0, stream>>>(srcv, dstv, bcur, bkt);
  bktscan_kernel<<<1, 256, 0, stream>>>(bcur, boff, row_ptr);
  histC_kernel<<<NBKT, 256, 0, stream>>>(bcur, bkt, boff, row_ptr, dis, NNODES);
  scatB_kernel<<<NBKT, 256, 0, stream>>>(bcur, bkt, row_ptr, dis, csr, NNODES);
  wprep_kernel<<<(512 * 128 + 160 * 128 + 255) / 256, 256, 0, stream>>>(W1, W2, W1t, W2pt);
  copyx_kernel<<<((NNODES * 32) + 255) / 256, 256, 0, stream>>>(x, P, NNODES);

  const int prop_blocks = (NNODES * 64 + 255) / 256;
  // Layer 1: P blocks k = A_hat^k x  (bf16, row stride 512)
  for (int k = 1; k <= KHOP; ++k)
    prop128c_kernel<<<prop_blocks, 256, 0, stream>>>(P + 128 * (k - 1), P + 128 * k,
                                                     row_ptr, csr, NNODES);
  const int gemm_blocks = (NNODES + 63) / 64;  // 784; rows < NROWP
  gemm1m_kernel<<<gemm_blocks, 256, 0, stream>>>(P, W1t, b1, H);
  gemm2m_kernel<<<gemm_blocks, 256, 0, stream>>>(H, W2pt, G);
  // Horner (bf16 storage, fp32 accum): tb = A*G3 + G2 ; t2 = A*tb + G1 ; out = lsm(A*t2 + G0 + b2)
  prop40c_kernel<<<prop_blocks, 256, 0, stream>>>(G3, G2, tb, row_ptr, csr, NNODES);
  prop40c_kernel<<<prop_blocks, 256, 0, stream>>>(tb, G1, t2, row_ptr, csr, NNODES);
  prop40c_lsm_kernel<<<prop_blocks, 256, 0, stream>>>(t2, G0, b2, out, row_ptr, csr, NNODES);
}

// Round 12
// 229.206 us; speedup vs baseline: 1.4517x; 1.0028x over previous
//
#include <hip/hip_runtime.h>
#include <hip/hip_bf16.h>

#define NNODES 50000
#define NROWP  50176   // padded row count (multiple of 64) for GEMM tiles
#define NEDGES 800000
#define KHOP 3
#define NBKT 196       // ceil(50176/256) buckets of 256 nodes
#define BCAP 6144      // entries per bucket (mean 4082, sd ~64 -> safe)
#define ABLK 800       // pass-A blocks
#define ACH  1000      // edges per pass-A block

typedef __attribute__((ext_vector_type(8))) short short8v;
typedef __attribute__((ext_vector_type(8))) __bf16 bf16x8;
typedef __attribute__((ext_vector_type(4))) float f32x4;

__device__ inline unsigned short f2bf(float f) {
  unsigned u = __builtin_bit_cast(unsigned, f);
  u += 0x7fffu + ((u >> 16) & 1u);   // RNE
  return (unsigned short)(u >> 16);
}
__device__ inline float bflo(unsigned u) { return __builtin_bit_cast(float, u << 16); }
__device__ inline float bfhi(unsigned u) { return __builtin_bit_cast(float, u & 0xffff0000u); }

__device__ inline void gload_lds16(const void* g, void* l) {
  __builtin_amdgcn_global_load_lds(
      (const __attribute__((address_space(1))) unsigned int*)g,
      (__attribute__((address_space(3))) unsigned int*)l, 16, 0, 0);
}

__device__ inline f32x4 mfma_bf16(bf16x8 a, bf16x8 b, f32x4 c) {
  return __builtin_amdgcn_mfma_f32_16x16x32_bf16(a, b, c, 0, 0, 0);
}

__device__ inline void fma8(float* acc, float w, short8v v) {
  uint4 u = __builtin_bit_cast(uint4, v);
  acc[0] = fmaf(w, bflo(u.x), acc[0]);
  acc[1] = fmaf(w, bfhi(u.x), acc[1]);
  acc[2] = fmaf(w, bflo(u.y), acc[2]);
  acc[3] = fmaf(w, bfhi(u.y), acc[3]);
  acc[4] = fmaf(w, bflo(u.z), acc[4]);
  acc[5] = fmaf(w, bfhi(u.z), acc[5]);
  acc[6] = fmaf(w, bflo(u.w), acc[6]);
  acc[7] = fmaf(w, bfhi(u.w), acc[7]);
}

__device__ inline void fma4(float* acc, float w, uint2 v) {
  acc[0] = fmaf(w, bflo(v.x), acc[0]);
  acc[1] = fmaf(w, bfhi(v.x), acc[1]);
  acc[2] = fmaf(w, bflo(v.y), acc[2]);
  acc[3] = fmaf(w, bfhi(v.y), acc[3]);
}

// ---------------- Pass A: bucket edges by dst>>8 ----------------
__global__ __launch_bounds__(256) void bucketA_kernel(
    const int* __restrict__ src, const int* __restrict__ dst,
    int* __restrict__ bcur, int2* __restrict__ bkt) {
  __shared__ int2 eb[ACH];
  __shared__ int hist[256];
  __shared__ int base[256];
  int tid = threadIdx.x;
  int e0 = blockIdx.x * ACH;
  int cnt = NEDGES - e0; if (cnt > ACH) cnt = ACH;
  hist[tid] = 0;
  __syncthreads();
  for (int i = tid; i < cnt; i += 256) {
    int s = src[e0 + i], d = dst[e0 + i];
    eb[i] = make_int2(s, d);
    atomicAdd(&hist[d >> 8], 1);
  }
  __syncthreads();
  base[tid] = atomicAdd(&bcur[tid], hist[tid]);
  hist[tid] = 0;
  __syncthreads();
  for (int i = tid; i < cnt; i += 256) {
    int2 e = eb[i];
    int b = e.y >> 8;
    int off = atomicAdd(&hist[b], 1);
    bkt[(size_t)b * BCAP + base[b] + off] = e;
  }
}

// ---------------- scan bucket totals -> bucket offsets ----------------
__global__ __launch_bounds__(256) void bktscan_kernel(
    const int* __restrict__ bcur, int* __restrict__ boff, int* __restrict__ row_ptr) {
  __shared__ int sd[256];
  int tid = threadIdx.x;
  int own = (tid < NBKT) ? bcur[tid] : 0;
  sd[tid] = own;
  __syncthreads();
  for (int o = 1; o < 256; o <<= 1) {
    int t = (tid >= o) ? sd[tid - o] : 0;
    __syncthreads();
    sd[tid] += t;
    __syncthreads();
  }
  if (tid < NBKT) boff[tid] = sd[tid] - own;   // exclusive
  if (tid == 255) row_ptr[NNODES] = sd[255];   // total edges
}

// ---------------- per-bucket histogram + intra-bucket scan -> row_ptr, dis ----------------
__global__ __launch_bounds__(256) void histC_kernel(
    const int* __restrict__ bcur, const int2* __restrict__ bkt,
    const int* __restrict__ boff, int* __restrict__ row_ptr,
    float* __restrict__ dis, int n) {
  __shared__ int h[256];
  __shared__ int sc[256];
  int b = blockIdx.x, tid = threadIdx.x;
  h[tid] = 0;
  __syncthreads();
  int sz = bcur[b];
  for (int i = tid; i < sz; i += 256)
    atomicAdd(&h[bkt[(size_t)b * BCAP + i].y & 255], 1);
  __syncthreads();
  int own = h[tid];
  sc[tid] = own;
  __syncthreads();
  for (int o = 1; o < 256; o <<= 1) {
    int t = (tid >= o) ? sc[tid - o] : 0;
    __syncthreads();
    sc[tid] += t;
    __syncthreads();
  }
  int node = b * 256 + tid;
  if (node < n) {
    row_ptr[node] = boff[b] + sc[tid] - own;
    dis[node] = (own > 0) ? rsqrtf((float)own) : 0.f;
  }
}

// ---------------- Pass B: per-bucket scatter into CSR ----------------
__global__ __launch_bounds__(256) void scatB_kernel(
    const int* __restrict__ bcur, const int2* __restrict__ bkt,
    const int* __restrict__ row_ptr, const float* __restrict__ dis,
    int2* __restrict__ csr, int n) {
  __shared__ int cur[256];
  int b = blockIdx.x, tid = threadIdx.x;
  int node = b * 256 + tid;
  cur[tid] = (node < n) ? row_ptr[node] : 0;
  __syncthreads();
  int sz = bcur[b];
  for (int i = tid; i < sz; i += 256) {
    int2 e = bkt[(size_t)b * BCAP + i];
    int pos = atomicAdd(&cur[e.y & 255], 1);
    int2 ent;
    ent.x = e.x;
    ent.y = __float_as_int(dis[e.x] * dis[e.y]);
    csr[pos] = ent;
  }
}

// ---------------- fused weight transforms ----------------
__global__ void wprep_kernel(const float* __restrict__ W1, const float* __restrict__ W2,
                             unsigned short* __restrict__ W1t,
                             unsigned short* __restrict__ W2pt) {
  int t = blockIdx.x * blockDim.x + threadIdx.x;
  if (t < 512 * 128) {
    int c = t >> 9, k = t & 511;
    W1t[t] = f2bf(W1[(size_t)k * 128 + c]);
  } else if (t < 512 * 128 + 160 * 128) {
    int u = t - 512 * 128;
    int q = u >> 7, r = u & 127;
    int k = q / 40, c = q - k * 40;
    W2pt[u] = f2bf(W2[(size_t)(k * 128 + r) * 40 + c]);
  }
}

// ---------------- x -> bf16 into P block 0 ----------------
__global__ void copyx_kernel(const float* __restrict__ x, unsigned short* __restrict__ P, int n) {
  int t = blockIdx.x * blockDim.x + threadIdx.x;
  int i = t >> 5;
  int c4 = (t & 31) << 2;
  if (i < n) {
    float4 v = *(const float4*)&x[(size_t)i * 128 + c4];
    unsigned lo = (unsigned)f2bf(v.x) | ((unsigned)f2bf(v.y) << 16);
    unsigned hi = (unsigned)f2bf(v.z) | ((unsigned)f2bf(v.w) << 16);
    uint2 o; o.x = lo; o.y = hi;
    *(uint2*)&P[(size_t)i * 512 + c4] = o;
  }
}

// ---------------- 128-dim bf16 propagation: 4 slots x 16 lanes, 4x-pipelined ----------------
__global__ __launch_bounds__(256) void prop128c_kernel(
    const unsigned short* __restrict__ in, unsigned short* __restrict__ out,
    const int* __restrict__ row_ptr, const int2* __restrict__ csr, int n) {
  int node = (int)((blockIdx.x * blockDim.x + threadIdx.x) >> 6);
  int lane = threadIdx.x & 63;
  if (node >= n) return;
  int beg = row_ptr[node], end = row_ptr[node + 1];
  int deg = end - beg;
  int2 ent = make_int2(0, 0);
  if (lane < deg) ent = csr[beg + lane];
  const int grp = lane >> 4, sub = lane & 15;
  float acc[8] = {0.f, 0.f, 0.f, 0.f, 0.f, 0.f, 0.f, 0.f};
  int m = deg < 64 ? deg : 64;
  int j = 0;
  // 16 edges per iteration, four independent 1KB loads in flight
  for (; j + 16 <= m; j += 16) {
    int s0 = __shfl(ent.x, j + grp, 64);
    float w0 = __int_as_float(__shfl(ent.y, j + grp, 64));
    int s1 = __shfl(ent.x, j + 4 + grp, 64);
    float w1 = __int_as_float(__shfl(ent.y, j + 4 + grp, 64));
    int s2 = __shfl(ent.x, j + 8 + grp, 64);
    float w2 = __int_as_float(__shfl(ent.y, j + 8 + grp, 64));
    int s3 = __shfl(ent.x, j + 12 + grp, 64);
    float w3 = __int_as_float(__shfl(ent.y, j + 12 + grp, 64));
    short8v v0 = *(const short8v*)(in + (size_t)s0 * 512 + sub * 8);
    short8v v1 = *(const short8v*)(in + (size_t)s1 * 512 + sub * 8);
    short8v v2 = *(const short8v*)(in + (size_t)s2 * 512 + sub * 8);
    short8v v3 = *(const short8v*)(in + (size_t)s3 * 512 + sub * 8);
    fma8(acc, w0, v0);
    fma8(acc, w1, v1);
    fma8(acc, w2, v2);
    fma8(acc, w3, v3);
  }
  for (; j + 8 <= m; j += 8) {
    int s0 = __shfl(ent.x, j + grp, 64);
    float w0 = __int_as_float(__shfl(ent.y, j + grp, 64));
    int s1 = __shfl(ent.x, j + 4 + grp, 64);
    float w1 = __int_as_float(__shfl(ent.y, j + 4 + grp, 64));
    short8v v0 = *(const short8v*)(in + (size_t)s0 * 512 + sub * 8);
    short8v v1 = *(const short8v*)(in + (size_t)s1 * 512 + sub * 8);
    fma8(acc, w0, v0);
    fma8(acc, w1, v1);
  }
  for (; j < m; j += 4) {
    int idx = j + grp;
    bool act = idx < m;
    int ic = act ? idx : m - 1;
    int s0 = __shfl(ent.x, ic, 64);
    float w0 = __int_as_float(__shfl(ent.y, ic, 64));
    if (!act) w0 = 0.f;
    short8v v0 = *(const short8v*)(in + (size_t)s0 * 512 + sub * 8);
    fma8(acc, w0, v0);
  }
  // rare tail: deg > 64 (slot 0 only contributes)
  for (int t = beg + 64; t < end; ++t) {
    int2 e0 = csr[t];
    float w0 = (grp == 0) ? __int_as_float(e0.y) : 0.f;
    short8v v = *(const short8v*)(in + (size_t)e0.x * 512 + sub * 8);
    fma8(acc, w0, v);
  }
#pragma unroll
  for (int i = 0; i < 8; ++i) {
    acc[i] += __shfl_xor(acc[i], 16, 64);
    acc[i] += __shfl_xor(acc[i], 32, 64);
  }
  if (grp == 0) {
    uint4 r;
    r.x = (unsigned)f2bf(acc[0]) | ((unsigned)f2bf(acc[1]) << 16);
    r.y = (unsigned)f2bf(acc[2]) | ((unsigned)f2bf(acc[3]) << 16);
    r.z = (unsigned)f2bf(acc[4]) | ((unsigned)f2bf(acc[5]) << 16);
    r.w = (unsigned)f2bf(acc[6]) | ((unsigned)f2bf(acc[7]) << 16);
    *(uint4*)(out + (size_t)node * 512 + sub * 8) = r;
  }
}

// ---------------- fused GEMM1+GEMM2 (MFMA): H tile stays in LDS ----------------
// per 64-row block: H = relu(P[64,512] @ W1 + b1) -> LDS [64][136]
// then Gk[64,40] = H @ W2p (K=128), written as 4 x [NROWP][64] bf16 blocks
__global__ __launch_bounds__(256) void gemm12_kernel(
    const unsigned short* __restrict__ A,    // P [NROWP][512] bf16
    const unsigned short* __restrict__ B1t,  // W1t [128][512] bf16
    const float* __restrict__ bias,          // b1
    const unsigned short* __restrict__ B2t,  // W2pt [160][128] bf16
    unsigned short* __restrict__ G) {        // 4 x [NROWP][64] bf16 (cols 40..63 pad)
  __shared__ short smem[2048 + 4096 + 64 * 136];
  short* As  = smem;                 // 64x32
  short* Bs1 = smem + 2048;          // 128x32
  short* Ht  = smem + 2048 + 4096;   // 64x136 (pad kills stride-128 bank conflict)
  short* Bs2c = smem;                // gemm2 W2pt chunk 160x32, reuses As+Bs1 (6144 >= 5120)
  const int tid = threadIdx.x;
  const int lane = tid & 63;
  const int w = tid >> 6;
  const int wr = w & 1;
  const int wc = w >> 1;
  const int row0 = blockIdx.x * 64;
  const int lrow = lane >> 2;
  const int lkp = lane & 3;
  const int kg = lane >> 4, rr = lane & 15;

  // ---- GEMM1 phase ----
  f32x4 acc[2][4];
#pragma unroll
  for (int i = 0; i < 2; ++i)
#pragma unroll
    for (int j = 0; j < 4; ++j) acc[i][j] = (f32x4)0.f;

  for (int k0 = 0; k0 < 512; k0 += 32) {
    gload_lds16(A + (size_t)(row0 + w * 16 + lrow) * 512 + k0 + lkp * 8, &As[w * 512]);
    gload_lds16(B1t + (size_t)(w * 16 + lrow) * 512 + k0 + lkp * 8, &Bs1[w * 512]);
    gload_lds16(B1t + (size_t)((w + 4) * 16 + lrow) * 512 + k0 + lkp * 8, &Bs1[(w + 4) * 512]);
    __syncthreads();
    bf16x8 af[2], bfr[4];
#pragma unroll
    for (int mr = 0; mr < 2; ++mr)
      af[mr] = __builtin_bit_cast(bf16x8,
          *(const short8v*)&As[(wr * 32 + mr * 16 + rr) * 32 + kg * 8]);
#pragma unroll
    for (int nr = 0; nr < 4; ++nr)
      bfr[nr] = __builtin_bit_cast(bf16x8,
          *(const short8v*)&Bs1[(wc * 64 + nr * 16 + rr) * 32 + kg * 8]);
#pragma unroll
    for (int mr = 0; mr < 2; ++mr)
#pragma unroll
      for (int nr = 0; nr < 4; ++nr)
        acc[mr][nr] = mfma_bf16(af[mr], bfr[nr], acc[mr][nr]);
    __syncthreads();
  }
  // bias + relu -> Ht (LDS)
  {
    const int cg = lane >> 4, cl = lane & 15;
#pragma unroll
    for (int mr = 0; mr < 2; ++mr)
#pragma unroll
      for (int nr = 0; nr < 4; ++nr) {
        int col = wc * 64 + nr * 16 + cl;
        float bv = bias[col];
#pragma unroll
        for (int j = 0; j < 4; ++j) {
          int lr = wr * 32 + mr * 16 + cg * 4 + j;
          Ht[lr * 136 + col] = (short)f2bf(fmaxf(acc[mr][nr][j] + bv, 0.f));
        }
      }
  }
  __syncthreads();

  // ---- GEMM2 phase: wave w handles rows w*16..w*16+15 ----
  f32x4 acc2[10];
#pragma unroll
  for (int i = 0; i < 10; ++i) acc2[i] = (f32x4)0.f;

  for (int k0 = 0; k0 < 128; k0 += 32) {
    for (int c = w; c < 10; c += 4)
      gload_lds16(B2t + (size_t)(c * 16 + lrow) * 128 + k0 + lkp * 8, &Bs2c[c * 512]);
    __syncthreads();
    bf16x8 af = __builtin_bit_cast(bf16x8,
        *(const short8v*)&Ht[(w * 16 + rr) * 136 + k0 + kg * 8]);
#pragma unroll
    for (int nr = 0; nr < 10; ++nr) {
      bf16x8 bfr = __builtin_bit_cast(bf16x8,
          *(const short8v*)&Bs2c[(nr * 16 + rr) * 32 + kg * 8]);
      acc2[nr] = mfma_bf16(af, bfr, acc2[nr]);
    }
    __syncthreads();
  }
  {
    const int cg = lane >> 4, cl = lane & 15;
#pragma unroll
    for (int nr = 0; nr < 10; ++nr) {
      int col = nr * 16 + cl;      // 0..159
      int k = col / 40;            // hop block
      int o = col - k * 40;
#pragma unroll
      for (int j = 0; j < 4; ++j) {
        int row = row0 + w * 16 + cg * 4 + j;
        G[(size_t)k * NROWP * 64 + (size_t)row * 64 + o] = f2bf(acc2[nr][j]);
      }
    }
  }
}

// ---------------- 40(64-pad)-dim propagation: 4 slots x 16 lanes, 4x-pipelined ----------------
__global__ __launch_bounds__(256) void prop40c_kernel(
    const unsigned short* __restrict__ in,   // [n][64] bf16 (pad cols garbage-ok)
    const unsigned short* __restrict__ add,  // [n][64]
    unsigned short* __restrict__ out,        // [n][64]
    const int* __restrict__ row_ptr, const int2* __restrict__ csr, int n) {
  int node = (int)((blockIdx.x * blockDim.x + threadIdx.x) >> 6);
  int lane = threadIdx.x & 63;
  if (node >= n) return;
  int beg = row_ptr[node], end = row_ptr[node + 1];
  int deg = end - beg;
  int2 ent = make_int2(0, 0);
  if (lane < deg) ent = csr[beg + lane];
  const int grp = lane >> 4, sub = lane & 15;
  float acc[4] = {0.f, 0.f, 0.f, 0.f};
  if (grp == 0) {
    uint2 a = *(const uint2*)(add + (size_t)node * 64 + sub * 4);
    acc[0] = bflo(a.x); acc[1] = bfhi(a.x);
    acc[2] = bflo(a.y); acc[3] = bfhi(a.y);
  }
  int m = deg < 64 ? deg : 64;
  int j = 0;
  for (; j + 16 <= m; j += 16) {
    int s0 = __shfl(ent.x, j + grp, 64);
    float w0 = __int_as_float(__shfl(ent.y, j + grp, 64));
    int s1 = __shfl(ent.x, j + 4 + grp, 64);
    float w1 = __int_as_float(__shfl(ent.y, j + 4 + grp, 64));
    int s2 = __shfl(ent.x, j + 8 + grp, 64);
    float w2 = __int_as_float(__shfl(ent.y, j + 8 + grp, 64));
    int s3 = __shfl(ent.x, j + 12 + grp, 64);
    float w3 = __int_as_float(__shfl(ent.y, j + 12 + grp, 64));
    uint2 v0 = *(const uint2*)(in + (size_t)s0 * 64 + sub * 4);
    uint2 v1 = *(const uint2*)(in + (size_t)s1 * 64 + sub * 4);
    uint2 v2 = *(const uint2*)(in + (size_t)s2 * 64 + sub * 4);
    uint2 v3 = *(const uint2*)(in + (size_t)s3 * 64 + sub * 4);
    fma4(acc, w0, v0);
    fma4(acc, w1, v1);
    fma4(acc, w2, v2);
    fma4(acc, w3, v3);
  }
  for (; j + 8 <= m; j += 8) {
    int s0 = __shfl(ent.x, j + grp, 64);
    float w0 = __int_as_float(__shfl(ent.y, j + grp, 64));
    int s1 = __shfl(ent.x, j + 4 + grp, 64);
    float w1 = __int_as_float(__shfl(ent.y, j + 4 + grp, 64));
    uint2 v0 = *(const uint2*)(in + (size_t)s0 * 64 + sub * 4);
    uint2 v1 = *(const uint2*)(in + (size_t)s1 * 64 + sub * 4);
    fma4(acc, w0, v0);
    fma4(acc, w1, v1);
  }
  for (; j < m; j += 4) {
    int idx = j + grp;
    bool act = idx < m;
    int ic = act ? idx : m - 1;
    int s0 = __shfl(ent.x, ic, 64);
    float w0 = __int_as_float(__shfl(ent.y, ic, 64));
    if (!act) w0 = 0.f;
    uint2 v0 = *(const uint2*)(in + (size_t)s0 * 64 + sub * 4);
    fma4(acc, w0, v0);
  }
  for (int t = beg + 64; t < end; ++t) {
    int2 e0 = csr[t];
    float w = (grp == 0) ? __int_as_float(e0.y) : 0.f;
    uint2 v = *(const uint2*)(in + (size_t)e0.x * 64 + sub * 4);
    fma4(acc, w, v);
  }
#pragma unroll
  for (int i = 0; i < 4; ++i) {
    acc[i] += __shfl_xor(acc[i], 16, 64);
    acc[i] += __shfl_xor(acc[i], 32, 64);
  }
  if (grp == 0) {
    uint2 r;
    r.x = (unsigned)f2bf(acc[0]) | ((unsigned)f2bf(acc[1]) << 16);
    r.y = (unsigned)f2bf(acc[2]) | ((unsigned)f2bf(acc[3]) << 16);
    *(uint2*)(out + (size_t)node * 64 + sub * 4) = r;
  }
}

// ---------------- final hop fused with bias + log_softmax ----------------
__global__ __launch_bounds__(256) void prop40c_lsm_kernel(
    const unsigned short* __restrict__ in,   // [n][64]
    const unsigned short* __restrict__ add,  // [n][64]
    const float* __restrict__ b2,
    float* __restrict__ out,                 // [n][40] f32
    const int* __restrict__ row_ptr, const int2* __restrict__ csr, int n) {
  int node = (int)((blockIdx.x * blockDim.x + threadIdx.x) >> 6);
  int lane = threadIdx.x & 63;
  if (node >= n) return;
  int beg = row_ptr[node], end = row_ptr[node + 1];
  int deg = end - beg;
  int2 ent = make_int2(0, 0);
  if (lane < deg) ent = csr[beg + lane];
  const int grp = lane >> 4, sub = lane & 15;
  float acc[4] = {0.f, 0.f, 0.f, 0.f};
  if (grp == 0) {
    uint2 a = *(const uint2*)(add + (size_t)node * 64 + sub * 4);
    acc[0] = bflo(a.x); acc[1] = bfhi(a.x);
    acc[2] = bflo(a.y); acc[3] = bfhi(a.y);
  }
  int m = deg < 64 ? deg : 64;
  int j = 0;
  for (; j + 16 <= m; j += 16) {
    int s0 = __shfl(ent.x, j + grp, 64);
    float w0 = __int_as_float(__shfl(ent.y, j + grp, 64));
    int s1 = __shfl(ent.x, j + 4 + grp, 64);
    float w1 = __int_as_float(__shfl(ent.y, j + 4 + grp, 64));
    int s2 = __shfl(ent.x, j + 8 + grp, 64);
    float w2 = __int_as_float(__shfl(ent.y, j + 8 + grp, 64));
    int s3 = __shfl(ent.x, j + 12 + grp, 64);
    float w3 = __int_as_float(__shfl(ent.y, j + 12 + grp, 64));
    uint2 v0 = *(const uint2*)(in + (size_t)s0 * 64 + sub * 4);
    uint2 v1 = *(const uint2*)(in + (size_t)s1 * 64 + sub * 4);
    uint2 v2 = *(const uint2*)(in + (size_t)s2 * 64 + sub * 4);
    uint2 v3 = *(const uint2*)(in + (size_t)s3 * 64 + sub * 4);
    fma4(acc, w0, v0);
    fma4(acc, w1, v1);
    fma4(acc, w2, v2);
    fma4(acc, w3, v3);
  }
  for (; j + 8 <= m; j += 8) {
    int s0 = __shfl(ent.x, j + grp, 64);
    float w0 = __int_as_float(__shfl(ent.y, j + grp, 64));
    int s1 = __shfl(ent.x, j + 4 + grp, 64);
    float w1 = __int_as_float(__shfl(ent.y, j + 4 + grp, 64));
    uint2 v0 = *(const uint2*)(in + (size_t)s0 * 64 + sub * 4);
    uint2 v1 = *(const uint2*)(in + (size_t)s1 * 64 + sub * 4);
    fma4(acc, w0, v0);
    fma4(acc, w1, v1);
  }
  for (; j < m; j += 4) {
    int idx = j + grp;
    bool act = idx < m;
    int ic = act ? idx : m - 1;
    int s0 = __shfl(ent.x, ic, 64);
    float w0 = __int_as_float(__shfl(ent.y, ic, 64));
    if (!act) w0 = 0.f;
    uint2 v0 = *(const uint2*)(in + (size_t)s0 * 64 + sub * 4);
    fma4(acc, w0, v0);
  }
  for (int t = beg + 64; t < end; ++t) {
    int2 e0 = csr[t];
    float w = (grp == 0) ? __int_as_float(e0.y) : 0.f;
    uint2 v = *(const uint2*)(in + (size_t)e0.x * 64 + sub * 4);
    fma4(acc, w, v);
  }
#pragma unroll
  for (int i = 0; i < 4; ++i) {
    acc[i] += __shfl_xor(acc[i], 16, 64);
    acc[i] += __shfl_xor(acc[i], 32, 64);
  }
  // every lane now holds the full sums for cols sub*4..sub*4+3
  bool val = (sub < 10);
  float vv[4];
  if (val) {
    float4 bv = *(const float4*)(b2 + sub * 4);
    vv[0] = acc[0] + bv.x; vv[1] = acc[1] + bv.y;
    vv[2] = acc[2] + bv.z; vv[3] = acc[3] + bv.w;
  } else {
    vv[0] = vv[1] = vv[2] = vv[3] = -__builtin_inff();
  }
  float mx = fmaxf(fmaxf(vv[0], vv[1]), fmaxf(vv[2], vv[3]));
#pragma unroll
  for (int o = 1; o < 16; o <<= 1) mx = fmaxf(mx, __shfl_xor(mx, o, 64));
  float s = 0.f;
  if (val)
    s = expf(vv[0] - mx) + expf(vv[1] - mx) + expf(vv[2] - mx) + expf(vv[3] - mx);
#pragma unroll
  for (int o = 1; o < 16; o <<= 1) s += __shfl_xor(s, o, 64);
  if (grp == 0 && val) {
    float ls = logf(s);
    float4 o4;
    o4.x = vv[0] - mx - ls; o4.y = vv[1] - mx - ls;
    o4.z = vv[2] - mx - ls; o4.w = vv[3] - mx - ls;
    *(float4*)(out + (size_t)node * 40 + sub * 4) = o4;
  }
}

extern "C" void kernel_launch(void* const* d_in, const int* in_sizes, int n_in,
                              void* d_out, int out_size, void* d_ws, size_t ws_size,
                              hipStream_t stream) {
  const float* x  = (const float*)d_in[0];
  const int*   ei = (const int*)d_in[1];
  const float* W1 = (const float*)d_in[2];
  const float* b1 = (const float*)d_in[3];
  const float* W2 = (const float*)d_in[4];
  const float* b2 = (const float*)d_in[5];
  const int* srcv = ei;
  const int* dstv = ei + NEDGES;
  float* out = (float*)d_out;

  char* wsb = (char*)d_ws;
  size_t off = 0;
  auto alloc = [&](size_t bytes) {
    char* p = wsb + off;
    off += (bytes + 255) & ~(size_t)255;
    return p;
  };
  float*          dis     = (float*)          alloc((size_t)NNODES * 4);
  int*            row_ptr = (int*)            alloc(((size_t)NNODES + 1) * 4);
  int*            bcur    = (int*)            alloc((size_t)256 * 4);
  int*            boff    = (int*)            alloc((size_t)NBKT * 4);
  int2*           bkt     = (int2*)           alloc((size_t)NBKT * BCAP * 8);
  int2*           csr     = (int2*)           alloc((size_t)NEDGES * 8);
  unsigned short* W1t     = (unsigned short*) alloc((size_t)128 * 512 * 2);
  unsigned short* W2pt    = (unsigned short*) alloc((size_t)160 * 128 * 2);
  unsigned short* P       = (unsigned short*) alloc((size_t)NROWP * 512 * 2);
  unsigned short* G       = (unsigned short*) alloc((size_t)4 * NROWP * 64 * 2);
  unsigned short* tb      = (unsigned short*) alloc((size_t)NNODES * 64 * 2);
  unsigned short* t2      = (unsigned short*) alloc((size_t)NNODES * 64 * 2);

  unsigned short* G0 = G;
  unsigned short* G1 = G + (size_t)1 * NROWP * 64;
  unsigned short* G2 = G + (size_t)2 * NROWP * 64;
  unsigned short* G3 = G + (size_t)3 * NROWP * 64;

  hipMemsetAsync(bcur, 0, 256 * 4, stream);
  bucketA_kernel<<<ABLK, 256, 0, stream>>>(srcv, dstv, bcur, bkt);
  bktscan_kernel<<<1, 256, 0, stream>>>(bcur, boff, row_ptr);
  histC_kernel<<<NBKT, 256, 0, stream>>>(bcur, bkt, boff, row_ptr, dis, NNODES);
  scatB_kernel<<<NBKT, 256, 0, stream>>>(bcur, bkt, row_ptr, dis, csr, NNODES);
  wprep_kernel<<<(512 * 128 + 160 * 128 + 255) / 256, 256, 0, stream>>>(W1, W2, W1t, W2pt);
  copyx_kernel<<<((NNODES * 32) + 255) / 256, 256, 0, stream>>>(x, P, NNODES);

  const int prop_blocks = (NNODES * 64 + 255) / 256;
  // Layer 1: P blocks k = A_hat^k x  (bf16, row stride 512)
  for (int k = 1; k <= KHOP; ++k)
    prop128c_kernel<<<prop_blocks, 256, 0, stream>>>(P + 128 * (k - 1), P + 128 * k,
                                                     row_ptr, csr, NNODES);
  const int gemm_blocks = (NNODES + 63) / 64;  // 784; rows < NROWP
  gemm12_kernel<<<gemm_blocks, 256, 0, stream>>>(P, W1t, b1, W2pt, G);
  // Horner (bf16 storage, fp32 accum): tb = A*G3 + G2 ; t2 = A*tb + G1 ; out = lsm(A*t2 + G0 + b2)
  prop40c_kernel<<<prop_blocks, 256, 0, stream>>>(G3, G2, tb, row_ptr, csr, NNODES);
  prop40c_kernel<<<prop_blocks, 256, 0, stream>>>(tb, G1, t2, row_ptr, csr, NNODES);
  prop40c_lsm_kernel<<<prop_blocks, 256, 0, stream>>>(t2, G0, b2, out, row_ptr, csr, NNODES);
}